// Round 11
// baseline (325.474 us; speedup 1.0000x reference)
//
#include <hip/hip_runtime.h>
#include <hip/hip_fp16.h>
#include <math.h>

// ---------------------------------------------------------------------------
// ADSAGE: 2x SAGEConv (mean aggr) + softmax + GCNConv, fp32.
// Aggregate-after-GEMM (mean is linear). GEMMs on matrix cores via
// split-bf16 (3-term). CSR via 2-pass radix sort by dst.
// ALL gathered activations (p, r, tp) stored FP16 -> gather bytes halved.
// Gather kernels use 8 independent edge chains per lane for MLP.
// GEMM grids split along M (blockIdx.y) for occupancy.
// Pipeline:
//   p16,q = x @ [W1l|W1r]                        MFMA GEMM K=128 (p fp16)
//   h1  = relu(mean(p16) + q + b1l)              gather (half2 lanes)
//   r16,s = h1 @ [W2l|W2r]                       MFMA GEMM K=128 (r fp16)
//   h2  = softmax(mean(r16) + s + b2l)           gather + fused softmax
//   tp16 = (h2 @ Wg) * dinv[row]                 MFMA GEMM K=64 (fp16 out)
//   out = dinv*(sum_j tp[j] + tp[i]) + bg        gather (fp16 in, fp32 out)
// ---------------------------------------------------------------------------

typedef __attribute__((ext_vector_type(8))) short bf16x8;
typedef __attribute__((ext_vector_type(4))) float f32x4;

__device__ inline unsigned short f32_bf16_hi(float f) {
    unsigned int u = __builtin_bit_cast(unsigned int, f);
    u = (u + 0x7FFFu + ((u >> 16) & 1u)) >> 16;
    return (unsigned short)u;
}
__device__ inline float bf16_to_f32(unsigned short h) {
    unsigned int u = ((unsigned int)h) << 16;
    return __builtin_bit_cast(float, u);
}

// ----------------------- radix CSR build (by dst) --------------------------
__global__ void count_kernel(const int* __restrict__ dst, int* __restrict__ off,
                             int E, int NB, int BK) {
    __shared__ int hist[256];
    int t = threadIdx.x;
    hist[t] = 0;
    __syncthreads();
    int base = blockIdx.x * 8192;
    for (int i = t; i < 8192; i += 256) {
        int e = base + i;
        if (e < E) atomicAdd(&hist[dst[e] >> 8], 1);
    }
    __syncthreads();
    if (t < BK) off[1 + t * NB + blockIdx.x] = hist[t];
    if (blockIdx.x == 0 && t == 0) off[0] = 0;
}

__global__ void scan_reduce_kernel(const int* __restrict__ data, int* __restrict__ bsum, int n) {
    __shared__ int red[256];
    int t = threadIdx.x;
    int base = blockIdx.x * 2048 + t * 8;
    int s = 0;
    if (base + 8 <= n) {
        int4 a = *(const int4*)(data + base);
        int4 b = *(const int4*)(data + base + 4);
        s = a.x + a.y + a.z + a.w + b.x + b.y + b.z + b.w;
    } else {
        for (int i = 0; i < 8; ++i)
            if (base + i < n) s += data[base + i];
    }
    red[t] = s;
    __syncthreads();
    for (int off = 128; off > 0; off >>= 1) {
        if (t < off) red[t] += red[t + off];
        __syncthreads();
    }
    if (t == 0) bsum[blockIdx.x] = red[0];
}

__global__ void scan_offsets_kernel(int* __restrict__ bsum, int B) {
    if (threadIdx.x == 0 && blockIdx.x == 0) {
        int run = 0;
        for (int i = 0; i < B; ++i) { int v = bsum[i]; bsum[i] = run; run += v; }
    }
}

__global__ void scan_final_kernel(int* __restrict__ data, const int* __restrict__ bsum, int n) {
    __shared__ int tsum[256];
    int t = threadIdx.x;
    int base = blockIdx.x * 2048 + t * 8;
    int v[8];
    int s = 0;
#pragma unroll
    for (int i = 0; i < 8; ++i) {
        v[i] = (base + i < n) ? data[base + i] : 0;
        s += v[i];
    }
    tsum[t] = s;
    for (int off = 1; off < 256; off <<= 1) {
        __syncthreads();
        int u = (t >= off) ? tsum[t - off] : 0;
        __syncthreads();
        tsum[t] += u;
    }
    __syncthreads();
    int run = bsum[blockIdx.x] + tsum[t] - s;
#pragma unroll
    for (int i = 0; i < 8; ++i) {
        run += v[i];
        if (base + i < n) data[base + i] = run;
    }
}

__global__ void partition_kernel(const int* __restrict__ src, const int* __restrict__ dst,
                                 const int* __restrict__ off, unsigned* __restrict__ ebuf,
                                 int E, int NB, int BK) {
    __shared__ int cur[256];
    int t = threadIdx.x;
    if (t < BK) cur[t] = off[t * NB + blockIdx.x];
    __syncthreads();
    int base = blockIdx.x * 8192;
    for (int i = t; i < 8192; i += 256) {
        int e = base + i;
        if (e < E) {
            int d = dst[e];
            int pos = atomicAdd(&cur[d >> 8], 1);
            ebuf[pos] = ((unsigned)src[e] << 8) | (unsigned)(d & 255);
        }
    }
}

__global__ void finalize_kernel(const unsigned* __restrict__ ebuf, const int* __restrict__ off,
                                int* __restrict__ col, int* __restrict__ rowptr,
                                float* __restrict__ dinv, int N, int NB, int E) {
    __shared__ int hist[256], scn[256], cur[256];
    int b = blockIdx.x, t = threadIdx.x;
    int base = off[b * NB];
    int end  = off[(b + 1) * NB];
    int M = end - base;
    hist[t] = 0;
    __syncthreads();
    for (int i = t; i < M; i += 256) atomicAdd(&hist[ebuf[base + i] & 255u], 1);
    __syncthreads();
    scn[t] = hist[t];
    for (int o = 1; o < 256; o <<= 1) {
        __syncthreads();
        int u = (t >= o) ? scn[t - o] : 0;
        __syncthreads();
        scn[t] += u;
    }
    __syncthreads();
    int excl = scn[t] - hist[t];
    int node = b * 256 + t;
    if (node < N) {
        rowptr[node] = base + excl;
        dinv[node] = rsqrtf((float)(hist[t] + 1));
    }
    if (b == 0 && t == 0) rowptr[N] = E;
    cur[t] = base + excl;
    __syncthreads();
    for (int i = t; i < M; i += 256) {
        unsigned w = ebuf[base + i];
        int pos = atomicAdd(&cur[w & 255u], 1);
        col[pos] = (int)(w >> 8);
    }
}

// -------------------------- weight pre-pack --------------------------------
__global__ void packw_kernel(const float* __restrict__ W1l, const float* __restrict__ W1r,
                             const float* __restrict__ W2l, const float* __restrict__ W2r,
                             const float* __restrict__ Wg,
                             unsigned short* __restrict__ p1h, unsigned short* __restrict__ p1l,
                             unsigned short* __restrict__ p2h, unsigned short* __restrict__ p2l,
                             unsigned short* __restrict__ p3h, unsigned short* __restrict__ p3l) {
    int which = blockIdx.y;
    const float* W;
    unsigned short *hi, *lo;
    int K, Mp, colOff, T;
    if (which == 0)      { W = W1l; hi = p1h; lo = p1l; K = 128; Mp = 128; colOff = 0;   T = 16; }
    else if (which == 1) { W = W1r; hi = p1h; lo = p1l; K = 128; Mp = 128; colOff = 128; T = 16; }
    else if (which == 2) { W = W2l; hi = p2h; lo = p2l; K = 128; Mp = 64;  colOff = 0;   T = 8;  }
    else if (which == 3) { W = W2r; hi = p2h; lo = p2l; K = 128; Mp = 64;  colOff = 64;  T = 8;  }
    else                 { W = Wg;  hi = p3h; lo = p3l; K = 64;  Mp = 64;  colOff = 0;   T = 4;  }
    int idx = blockIdx.x * blockDim.x + threadIdx.x;
    if (idx >= K * Mp) return;
    int k = idx / Mp, m = idx % Mp;
    float w = W[(size_t)k * Mp + m];
    int colI = colOff + m;
    int s = k >> 5, kk = k & 31, qq = kk >> 3, j = kk & 7;
    int tt = colI >> 4, n = colI & 15;
    int lane = qq * 16 + n;
    size_t pos = ((size_t)(s * T + tt) * 64 + lane) * 8 + j;
    unsigned short h = f32_bf16_hi(w);
    hi[pos] = h;
    lo[pos] = f32_bf16_hi(w - bf16_to_f32(h));
}

// --------------------------- MFMA GEMM -------------------------------------
// out = A[N,K] @ Wpacked[K, M=Ttot*16]. Block handles TB tiles starting at
// tile blockIdx.y*TB. SPLIT: cols [0,H)->outA, [H,M)->outB fp32. A16: outA
// stored fp16 (lead dim H if SPLIT else M). rowScale: scale output row.
template <int K, int Ttot, int TB, bool SPLIT, bool A16>
__launch_bounds__(256)
__global__ void gemm_mfma_kernel(const float* __restrict__ A,
                                 const unsigned short* __restrict__ Whi,
                                 const unsigned short* __restrict__ Wlo,
                                 void* __restrict__ outAv, float* __restrict__ outB,
                                 const float* __restrict__ rowScale, int N) {
    constexpr int S = K / 32, M = Ttot * 16, H = SPLIT ? M / 2 : M;
    const int lane = threadIdx.x & 63;
    const int wave = threadIdx.x >> 6;
    const int m = lane & 15, q = lane >> 4;
    const int t0 = blockIdx.y * TB;
    const int row0 = blockIdx.x * 64 + wave * 16;
    int arow = row0 + m;
    if (arow >= N) arow = N - 1;       // clamp: only pollutes rows we don't store
    const float* ap = A + (size_t)arow * K + q * 8;

    f32x4 acc[TB];
#pragma unroll
    for (int t = 0; t < TB; ++t) acc[t] = (f32x4)(0.f);

#pragma unroll
    for (int s = 0; s < S; ++s) {
        float av[8];
        *(float4*)(av)     = *(const float4*)(ap + s * 32);
        *(float4*)(av + 4) = *(const float4*)(ap + s * 32 + 4);
        bf16x8 ahi, alo;
#pragma unroll
        for (int i = 0; i < 8; ++i) {
            unsigned short h = f32_bf16_hi(av[i]);
            ahi[i] = (short)h;
            alo[i] = (short)f32_bf16_hi(av[i] - bf16_to_f32(h));
        }
        const int base = (s * Ttot + t0) * 64 + lane;
        const bf16x8* whp = (const bf16x8*)Whi;
        const bf16x8* wlp = (const bf16x8*)Wlo;
#pragma unroll
        for (int t = 0; t < TB; ++t) {
            bf16x8 wh = whp[base + t * 64];
            bf16x8 wl = wlp[base + t * 64];
            acc[t] = __builtin_amdgcn_mfma_f32_16x16x32_bf16(ahi, wh, acc[t], 0, 0, 0);
            acc[t] = __builtin_amdgcn_mfma_f32_16x16x32_bf16(alo, wh, acc[t], 0, 0, 0);
            acc[t] = __builtin_amdgcn_mfma_f32_16x16x32_bf16(ahi, wl, acc[t], 0, 0, 0);
        }
    }

#pragma unroll
    for (int r = 0; r < 4; ++r) {
        int row = row0 + q * 4 + r;
        if (row < N) {
            float sc = rowScale ? rowScale[row] : 1.0f;
#pragma unroll
            for (int t = 0; t < TB; ++t) {
                int c = (t0 + t) * 16 + m;
                float v = acc[t][r] * sc;
                if (c < H) {
                    if (A16) ((__half*)outAv)[(size_t)row * H + c] = __float2half(v);
                    else     ((float*)outAv)[(size_t)row * H + c] = v;
                } else {
                    outB[(size_t)row * (M - H) + (c - H)] = v;
                }
            }
        }
    }
}

// ------------------------------ gathers ------------------------------------
// agg1: wave/node; lane owns features [lane*2, lane*2+1]; p fp16 (256B/row);
// 8 independent edge chains. h1 = relu(mean(p)+q+b1l), fp32 out.
__global__ void agg1_relu_kernel(const __half* __restrict__ p, const float* __restrict__ q,
                                 const int* __restrict__ rowptr, const int* __restrict__ col,
                                 const float* __restrict__ b1l,
                                 float* __restrict__ h1, int N) {
    int node = blockIdx.x * 4 + (threadIdx.x >> 6);
    if (node >= N) return;
    const int lane = threadIdx.x & 63;
    int s = rowptr[node], e = rowptr[node + 1];
    float2 a[8];
#pragma unroll
    for (int k = 0; k < 8; ++k) a[k] = make_float2(0.f, 0.f);
    int pp = s;
    for (; pp + 8 <= e; pp += 8) {
#pragma unroll
        for (int k = 0; k < 8; ++k) {
            int j = col[pp + k];
            float2 v = __half22float2(*(const __half2*)(p + (size_t)j * 128 + lane * 2));
            a[k].x += v.x; a[k].y += v.y;
        }
    }
    for (; pp < e; ++pp) {
        int j = col[pp];
        float2 v = __half22float2(*(const __half2*)(p + (size_t)j * 128 + lane * 2));
        a[0].x += v.x; a[0].y += v.y;
    }
    float ax = ((a[0].x + a[1].x) + (a[2].x + a[3].x)) + ((a[4].x + a[5].x) + (a[6].x + a[7].x));
    float ay = ((a[0].y + a[1].y) + (a[2].y + a[3].y)) + ((a[4].y + a[5].y) + (a[6].y + a[7].y));
    float inv = 1.0f / fmaxf((float)(e - s), 1.0f);
    float2 qv = *(const float2*)(q + (size_t)node * 128 + lane * 2);
    float2 bv = *(const float2*)(b1l + lane * 2);
    float2 r;
    r.x = fmaxf(ax * inv + qv.x + bv.x, 0.f);
    r.y = fmaxf(ay * inv + qv.y + bv.y, 0.f);
    *(float2*)(h1 + (size_t)node * 128 + lane * 2) = r;
}

// agg2+softmax: wave/node; lane owns feature [lane]; r fp16 (128B/row);
// 8 chains; fused softmax across the 64 lanes. h2 fp32.
__global__ void agg2_softmax_kernel(const __half* __restrict__ rr, const float* __restrict__ ss,
                                    const int* __restrict__ rowptr, const int* __restrict__ col,
                                    const float* __restrict__ b2l,
                                    float* __restrict__ h2, int N) {
    int node = blockIdx.x * 4 + (threadIdx.x >> 6);
    if (node >= N) return;
    int lane = threadIdx.x & 63;
    int s = rowptr[node], e = rowptr[node + 1];
    float a[8];
#pragma unroll
    for (int k = 0; k < 8; ++k) a[k] = 0.f;
    int p = s;
    for (; p + 8 <= e; p += 8) {
#pragma unroll
        for (int k = 0; k < 8; ++k)
            a[k] += __half2float(rr[(size_t)col[p + k] * 64 + lane]);
    }
    for (; p < e; ++p) a[0] += __half2float(rr[(size_t)col[p] * 64 + lane]);
    float acc = ((a[0] + a[1]) + (a[2] + a[3])) + ((a[4] + a[5]) + (a[6] + a[7]));
    float inv = 1.0f / fmaxf((float)(e - s), 1.0f);
    float v = acc * inv + ss[(size_t)node * 64 + lane] + b2l[lane];
    float mx = v;
#pragma unroll
    for (int o = 32; o > 0; o >>= 1) mx = fmaxf(mx, __shfl_xor(mx, o, 64));
    float ex = expf(v - mx);
    float ssum = ex;
#pragma unroll
    for (int o = 32; o > 0; o >>= 1) ssum += __shfl_xor(ssum, o, 64);
    h2[(size_t)node * 64 + lane] = ex / ssum;
}

// gcn: wave/node; lane owns feature [lane]; tp fp16 (128B/row, pre-scaled by
// dinv in gemm3 epilogue); 8 chains. out = dinv[i]*(sum_j tp[j]+tp[i]) + bg.
__global__ void gcn_agg_kernel(const __half* __restrict__ tp,
                               const int* __restrict__ rowptr, const int* __restrict__ col,
                               const float* __restrict__ dinv, const float* __restrict__ bg,
                               float* __restrict__ out, int N) {
    int node = blockIdx.x * 4 + (threadIdx.x >> 6);
    if (node >= N) return;
    int lane = threadIdx.x & 63;
    int s = rowptr[node], e = rowptr[node + 1];
    float a[8];
#pragma unroll
    for (int k = 0; k < 8; ++k) a[k] = 0.f;
    int p = s;
    for (; p + 8 <= e; p += 8) {
#pragma unroll
        for (int k = 0; k < 8; ++k)
            a[k] += __half2float(tp[(size_t)col[p + k] * 64 + lane]);
    }
    for (; p < e; ++p) a[0] += __half2float(tp[(size_t)col[p] * 64 + lane]);
    float acc = ((a[0] + a[1]) + (a[2] + a[3])) + ((a[4] + a[5]) + (a[6] + a[7]));
    float di = dinv[node];
    out[(size_t)node * 64 + lane] =
        (acc + __half2float(tp[(size_t)node * 64 + lane])) * di + bg[lane];
}

extern "C" void kernel_launch(void* const* d_in, const int* in_sizes, int n_in,
                              void* d_out, int out_size, void* d_ws, size_t ws_size,
                              hipStream_t stream) {
    const float* x = (const float*)d_in[0];
    const int* ei = (const int*)d_in[1];    // int32 per harness conversion
    const float* W1l = (const float*)d_in[2];
    const float* b1l = (const float*)d_in[3];
    const float* W1r = (const float*)d_in[4];
    const float* W2l = (const float*)d_in[5];
    const float* b2l = (const float*)d_in[6];
    const float* W2r = (const float*)d_in[7];
    const float* Wg  = (const float*)d_in[8];
    const float* bg  = (const float*)d_in[9];

    const int N = in_sizes[0] / 128;
    const int E = in_sizes[1] / 2;
    const int* srcp = ei;
    const int* dstp = ei + E;

    const int NB = (E + 8191) / 8192;       // partition blocks
    const int BK = (N + 255) >> 8;          // dst buckets
    const int len = BK * NB;

    // workspace layout
    float* ws = (float*)d_ws;
    float* q    = ws;                          // N*128 fp32 (alias: s)
    float* h1   = q + (size_t)N * 128;         // N*128 fp32 (alias: h2)
    float* dinv = h1 + (size_t)N * 128;        // N
    __half* p16 = (__half*)(dinv + N);         // N*128 half (alias: r16)
    __half* tp16 = p16 + (size_t)N * 128;      // N*64 half
    int* rowptr = (int*)(tp16 + (size_t)N * 64); // N+1
    int* off    = rowptr + (N + 1);            // len+2
    int* colbuf = off + len + 2;               // E
    unsigned* ebuf = (unsigned*)(colbuf + E);  // E
    int* bsum   = (int*)(ebuf + E);            // 32
    uintptr_t up = (uintptr_t)(bsum + 32);
    up = (up + 15) & ~(uintptr_t)15;
    unsigned short* p1h = (unsigned short*)up; // 32768 (128x256)
    unsigned short* p1l = p1h + 32768;
    unsigned short* p2h = p1l + 32768;         // 16384 (128x128)
    unsigned short* p2l = p2h + 16384;
    unsigned short* p3h = p2l + 16384;         // 4096 (64x64)
    unsigned short* p3l = p3h + 4096;

    __half* r16 = p16;                         // N*64 half (p16 dead after agg1)
    float* s  = q;                             // N*64
    float* h2 = h1;                            // N*64

    float* out = (float*)d_out;

    // --- CSR build (radix by dst) ---
    count_kernel<<<NB, 256, 0, stream>>>(dstp, off, E, NB, BK);
    const int sn = len + 1;
    const int SBs = (sn + 2047) / 2048;
    scan_reduce_kernel<<<SBs, 256, 0, stream>>>(off, bsum, sn);
    scan_offsets_kernel<<<1, 64, 0, stream>>>(bsum, SBs);
    scan_final_kernel<<<SBs, 256, 0, stream>>>(off, bsum, sn);
    partition_kernel<<<NB, 256, 0, stream>>>(srcp, dstp, off, ebuf, E, NB, BK);
    finalize_kernel<<<BK, 256, 0, stream>>>(ebuf, off, colbuf, rowptr, dinv, N, NB, E);

    packw_kernel<<<dim3(64, 5), 256, 0, stream>>>(W1l, W1r, W2l, W2r, Wg,
                                                  p1h, p1l, p2h, p2l, p3h, p3l);

    const int gb = (N + 63) / 64;
    const int ab = (N + 3) / 4;

    // gemm1: Ttot=16 tiles, 2 blocks of 8 (y=0 -> p16 cols, y=1 -> q cols)
    gemm_mfma_kernel<128, 16, 8, true, true><<<dim3(gb, 2), 256, 0, stream>>>(
        x, p1h, p1l, (void*)p16, q, nullptr, N);
    agg1_relu_kernel<<<ab, 256, 0, stream>>>(p16, q, rowptr, colbuf, b1l, h1, N);

    // gemm2: Ttot=8 tiles, 2 blocks of 4 (y=0 -> r16, y=1 -> s)
    gemm_mfma_kernel<128, 8, 4, true, true><<<dim3(gb, 2), 256, 0, stream>>>(
        h1, p2h, p2l, (void*)r16, s, nullptr, N);
    agg2_softmax_kernel<<<ab, 256, 0, stream>>>(r16, s, rowptr, colbuf, b2l, h2, N);

    // gemm3: Ttot=4 tiles, single block, fp16 output scaled by dinv
    gemm_mfma_kernel<64, 4, 4, false, true><<<dim3(gb, 1), 256, 0, stream>>>(
        h2, p3h, p3l, (void*)tp16, nullptr, dinv, N);
    gcn_agg_kernel<<<ab, 256, 0, stream>>>(tp16, rowptr, colbuf, dinv, bg, out, N);
}

// Round 12
// 305.951 us; speedup vs baseline: 1.0638x; 1.0638x over previous
//
#include <hip/hip_runtime.h>
#include <hip/hip_fp16.h>
#include <math.h>

// ---------------------------------------------------------------------------
// ADSAGE: 2x SAGEConv (mean aggr) + softmax + GCNConv, fp32.
// Aggregate-after-GEMM (mean is linear). GEMMs on matrix cores via
// split-bf16 (3-term). CSR via 2-pass radix sort by dst. Gathered
// activations (p16, r16, tp16) stored FP16. Register-resident fusion: the
// gather phase assigns lane (m,q) to features q*8+32s of node row0+m, which
// IS the MFMA A-fragment layout -> gather + epilogue + GEMM in one kernel,
// no LDS, no barrier, no h1/h2 global round trip.
// Pipeline:
//   p16,q = x @ [W1l|W1r]                        MFMA GEMM K=128 (p fp16)
//   r16,s = relu(mean(p16)+q+b1l) @ [W2l|W2r]    FUSED gather+GEMM K=128
//   tp16  = softmax(mean(r16)+s+b2l) @ Wg * dinv FUSED gather+softmax+GEMM
//   out   = dinv*(sum_j tp[j] + tp[i]) + bg      gather (fp16 in, fp32 out)
// ---------------------------------------------------------------------------

typedef __attribute__((ext_vector_type(8))) short bf16x8;
typedef __attribute__((ext_vector_type(4))) float f32x4;

__device__ inline unsigned short f32_bf16_hi(float f) {
    unsigned int u = __builtin_bit_cast(unsigned int, f);
    u = (u + 0x7FFFu + ((u >> 16) & 1u)) >> 16;
    return (unsigned short)u;
}
__device__ inline float bf16_to_f32(unsigned short h) {
    unsigned int u = ((unsigned int)h) << 16;
    return __builtin_bit_cast(float, u);
}

union H8 { float4 f4; __half2 h[4]; };

// ----------------------- radix CSR build (by dst) --------------------------
__global__ void count_kernel(const int* __restrict__ dst, int* __restrict__ off,
                             int E, int NB, int BK) {
    __shared__ int hist[256];
    int t = threadIdx.x;
    hist[t] = 0;
    __syncthreads();
    int base = blockIdx.x * 8192;
    for (int i = t; i < 8192; i += 256) {
        int e = base + i;
        if (e < E) atomicAdd(&hist[dst[e] >> 8], 1);
    }
    __syncthreads();
    if (t < BK) off[1 + t * NB + blockIdx.x] = hist[t];
    if (blockIdx.x == 0 && t == 0) off[0] = 0;
}

__global__ void scan_reduce_kernel(const int* __restrict__ data, int* __restrict__ bsum, int n) {
    __shared__ int red[256];
    int t = threadIdx.x;
    int base = blockIdx.x * 2048 + t * 8;
    int s = 0;
    if (base + 8 <= n) {
        int4 a = *(const int4*)(data + base);
        int4 b = *(const int4*)(data + base + 4);
        s = a.x + a.y + a.z + a.w + b.x + b.y + b.z + b.w;
    } else {
        for (int i = 0; i < 8; ++i)
            if (base + i < n) s += data[base + i];
    }
    red[t] = s;
    __syncthreads();
    for (int off = 128; off > 0; off >>= 1) {
        if (t < off) red[t] += red[t + off];
        __syncthreads();
    }
    if (t == 0) bsum[blockIdx.x] = red[0];
}

__global__ void scan_offsets_kernel(int* __restrict__ bsum, int B) {
    if (threadIdx.x == 0 && blockIdx.x == 0) {
        int run = 0;
        for (int i = 0; i < B; ++i) { int v = bsum[i]; bsum[i] = run; run += v; }
    }
}

__global__ void scan_final_kernel(int* __restrict__ data, const int* __restrict__ bsum, int n) {
    __shared__ int tsum[256];
    int t = threadIdx.x;
    int base = blockIdx.x * 2048 + t * 8;
    int v[8];
    int s = 0;
#pragma unroll
    for (int i = 0; i < 8; ++i) {
        v[i] = (base + i < n) ? data[base + i] : 0;
        s += v[i];
    }
    tsum[t] = s;
    for (int off = 1; off < 256; off <<= 1) {
        __syncthreads();
        int u = (t >= off) ? tsum[t - off] : 0;
        __syncthreads();
        tsum[t] += u;
    }
    __syncthreads();
    int run = bsum[blockIdx.x] + tsum[t] - s;
#pragma unroll
    for (int i = 0; i < 8; ++i) {
        run += v[i];
        if (base + i < n) data[base + i] = run;
    }
}

__global__ void partition_kernel(const int* __restrict__ src, const int* __restrict__ dst,
                                 const int* __restrict__ off, unsigned* __restrict__ ebuf,
                                 int E, int NB, int BK) {
    __shared__ int cur[256];
    int t = threadIdx.x;
    if (t < BK) cur[t] = off[t * NB + blockIdx.x];
    __syncthreads();
    int base = blockIdx.x * 8192;
    for (int i = t; i < 8192; i += 256) {
        int e = base + i;
        if (e < E) {
            int d = dst[e];
            int pos = atomicAdd(&cur[d >> 8], 1);
            ebuf[pos] = ((unsigned)src[e] << 8) | (unsigned)(d & 255);
        }
    }
}

__global__ void finalize_kernel(const unsigned* __restrict__ ebuf, const int* __restrict__ off,
                                int* __restrict__ col, int* __restrict__ rowptr,
                                float* __restrict__ dinv, int N, int NB, int E) {
    __shared__ int hist[256], scn[256], cur[256];
    int b = blockIdx.x, t = threadIdx.x;
    int base = off[b * NB];
    int end  = off[(b + 1) * NB];
    int M = end - base;
    hist[t] = 0;
    __syncthreads();
    for (int i = t; i < M; i += 256) atomicAdd(&hist[ebuf[base + i] & 255u], 1);
    __syncthreads();
    scn[t] = hist[t];
    for (int o = 1; o < 256; o <<= 1) {
        __syncthreads();
        int u = (t >= o) ? scn[t - o] : 0;
        __syncthreads();
        scn[t] += u;
    }
    __syncthreads();
    int excl = scn[t] - hist[t];
    int node = b * 256 + t;
    if (node < N) {
        rowptr[node] = base + excl;
        dinv[node] = rsqrtf((float)(hist[t] + 1));
    }
    if (b == 0 && t == 0) rowptr[N] = E;
    cur[t] = base + excl;
    __syncthreads();
    for (int i = t; i < M; i += 256) {
        unsigned w = ebuf[base + i];
        int pos = atomicAdd(&cur[w & 255u], 1);
        col[pos] = (int)(w >> 8);
    }
}

// -------------------------- weight pre-pack --------------------------------
__global__ void packw_kernel(const float* __restrict__ W1l, const float* __restrict__ W1r,
                             const float* __restrict__ W2l, const float* __restrict__ W2r,
                             const float* __restrict__ Wg,
                             unsigned short* __restrict__ p1h, unsigned short* __restrict__ p1l,
                             unsigned short* __restrict__ p2h, unsigned short* __restrict__ p2l,
                             unsigned short* __restrict__ p3h, unsigned short* __restrict__ p3l) {
    int which = blockIdx.y;
    const float* W;
    unsigned short *hi, *lo;
    int K, Mp, colOff, T;
    if (which == 0)      { W = W1l; hi = p1h; lo = p1l; K = 128; Mp = 128; colOff = 0;   T = 16; }
    else if (which == 1) { W = W1r; hi = p1h; lo = p1l; K = 128; Mp = 128; colOff = 128; T = 16; }
    else if (which == 2) { W = W2l; hi = p2h; lo = p2l; K = 128; Mp = 64;  colOff = 0;   T = 8;  }
    else if (which == 3) { W = W2r; hi = p2h; lo = p2l; K = 128; Mp = 64;  colOff = 64;  T = 8;  }
    else                 { W = Wg;  hi = p3h; lo = p3l; K = 64;  Mp = 64;  colOff = 0;   T = 4;  }
    int idx = blockIdx.x * blockDim.x + threadIdx.x;
    if (idx >= K * Mp) return;
    int k = idx / Mp, m = idx % Mp;
    float w = W[(size_t)k * Mp + m];
    int colI = colOff + m;
    int s = k >> 5, kk = k & 31, qq = kk >> 3, j = kk & 7;
    int tt = colI >> 4, n = colI & 15;
    int lane = qq * 16 + n;
    size_t pos = ((size_t)(s * T + tt) * 64 + lane) * 8 + j;
    unsigned short h = f32_bf16_hi(w);
    hi[pos] = h;
    lo[pos] = f32_bf16_hi(w - bf16_to_f32(h));
}

// --------------------------- MFMA GEMM (gemm1) -----------------------------
template <int K, int Ttot, int TB, bool SPLIT, bool A16>
__launch_bounds__(256)
__global__ void gemm_mfma_kernel(const float* __restrict__ A,
                                 const unsigned short* __restrict__ Whi,
                                 const unsigned short* __restrict__ Wlo,
                                 void* __restrict__ outAv, float* __restrict__ outB,
                                 const float* __restrict__ rowScale, int N) {
    constexpr int S = K / 32, M = Ttot * 16, H = SPLIT ? M / 2 : M;
    const int lane = threadIdx.x & 63;
    const int wave = threadIdx.x >> 6;
    const int m = lane & 15, q = lane >> 4;
    const int t0 = blockIdx.y * TB;
    const int row0 = blockIdx.x * 64 + wave * 16;
    int arow = row0 + m;
    if (arow >= N) arow = N - 1;
    const float* ap = A + (size_t)arow * K + q * 8;

    f32x4 acc[TB];
#pragma unroll
    for (int t = 0; t < TB; ++t) acc[t] = (f32x4)(0.f);

#pragma unroll
    for (int s = 0; s < S; ++s) {
        float av[8];
        *(float4*)(av)     = *(const float4*)(ap + s * 32);
        *(float4*)(av + 4) = *(const float4*)(ap + s * 32 + 4);
        bf16x8 ahi, alo;
#pragma unroll
        for (int i = 0; i < 8; ++i) {
            unsigned short h = f32_bf16_hi(av[i]);
            ahi[i] = (short)h;
            alo[i] = (short)f32_bf16_hi(av[i] - bf16_to_f32(h));
        }
        const int base = (s * Ttot + t0) * 64 + lane;
        const bf16x8* whp = (const bf16x8*)Whi;
        const bf16x8* wlp = (const bf16x8*)Wlo;
#pragma unroll
        for (int t = 0; t < TB; ++t) {
            bf16x8 wh = whp[base + t * 64];
            bf16x8 wl = wlp[base + t * 64];
            acc[t] = __builtin_amdgcn_mfma_f32_16x16x32_bf16(ahi, wh, acc[t], 0, 0, 0);
            acc[t] = __builtin_amdgcn_mfma_f32_16x16x32_bf16(alo, wh, acc[t], 0, 0, 0);
            acc[t] = __builtin_amdgcn_mfma_f32_16x16x32_bf16(ahi, wl, acc[t], 0, 0, 0);
        }
    }

#pragma unroll
    for (int r = 0; r < 4; ++r) {
        int row = row0 + q * 4 + r;
        if (row < N) {
            float sc = rowScale ? rowScale[row] : 1.0f;
#pragma unroll
            for (int t = 0; t < TB; ++t) {
                int c = (t0 + t) * 16 + m;
                float v = acc[t][r] * sc;
                if (c < H) {
                    if (A16) ((__half*)outAv)[(size_t)row * H + c] = __float2half(v);
                    else     ((float*)outAv)[(size_t)row * H + c] = v;
                } else {
                    outB[(size_t)row * (M - H) + (c - H)] = v;
                }
            }
        }
    }
}

// ------------------- FUSED: agg1+relu+gemm2 (K=128) ------------------------
// Lane (m,q) gathers feats [s*32+q*8 .. +7] (s=0..3) of node row0+m directly
// into MFMA A-fragment layout. No LDS, no barrier.
__launch_bounds__(256)
__global__ void sage2_fused_kernel(const __half* __restrict__ p16, const float* __restrict__ qarr,
                                   const int* __restrict__ rowptr, const int* __restrict__ col,
                                   const float* __restrict__ b1l,
                                   const unsigned short* __restrict__ Whi,
                                   const unsigned short* __restrict__ Wlo,
                                   __half* __restrict__ r16, float* __restrict__ sarr, int N) {
    const int lane = threadIdx.x & 63;
    const int wave = threadIdx.x >> 6;
    const int m = lane & 15, q = lane >> 4;
    const int row0 = blockIdx.x * 64 + wave * 16;
    int node = row0 + m;
    int nclamp = (node < N) ? node : (N - 1);
    int sIdx = rowptr[nclamp];
    int eIdx = (node < N) ? rowptr[nclamp + 1] : sIdx;

    float acc[4][8];
#pragma unroll
    for (int s = 0; s < 4; ++s)
#pragma unroll
        for (int i = 0; i < 8; ++i) acc[s][i] = 0.f;

    const __half* pb = p16 + q * 8;
    int ptr = sIdx;
    for (; ptr + 2 <= eIdx; ptr += 2) {
        int j0 = col[ptr], j1 = col[ptr + 1];
#pragma unroll
        for (int s = 0; s < 4; ++s) {
            H8 u0, u1;
            u0.f4 = *(const float4*)(pb + (size_t)j0 * 128 + s * 32);
            u1.f4 = *(const float4*)(pb + (size_t)j1 * 128 + s * 32);
#pragma unroll
            for (int k = 0; k < 4; ++k) {
                float2 f0 = __half22float2(u0.h[k]);
                float2 f1 = __half22float2(u1.h[k]);
                acc[s][2 * k]     += f0.x + f1.x;
                acc[s][2 * k + 1] += f0.y + f1.y;
            }
        }
    }
    if (ptr < eIdx) {
        int j0 = col[ptr];
#pragma unroll
        for (int s = 0; s < 4; ++s) {
            H8 u0;
            u0.f4 = *(const float4*)(pb + (size_t)j0 * 128 + s * 32);
#pragma unroll
            for (int k = 0; k < 4; ++k) {
                float2 f0 = __half22float2(u0.h[k]);
                acc[s][2 * k]     += f0.x;
                acc[s][2 * k + 1] += f0.y;
            }
        }
    }

    float inv = 1.0f / fmaxf((float)(eIdx - sIdx), 1.0f);
    bf16x8 ahi[4], alo[4];
#pragma unroll
    for (int s = 0; s < 4; ++s) {
        float qv[8], bv[8];
        *(float4*)(qv)     = *(const float4*)(qarr + (size_t)nclamp * 128 + s * 32 + q * 8);
        *(float4*)(qv + 4) = *(const float4*)(qarr + (size_t)nclamp * 128 + s * 32 + q * 8 + 4);
        *(float4*)(bv)     = *(const float4*)(b1l + s * 32 + q * 8);
        *(float4*)(bv + 4) = *(const float4*)(b1l + s * 32 + q * 8 + 4);
#pragma unroll
        for (int i = 0; i < 8; ++i) {
            float h = fmaxf(acc[s][i] * inv + qv[i] + bv[i], 0.f);
            unsigned short hb = f32_bf16_hi(h);
            ahi[s][i] = (short)hb;
            alo[s][i] = (short)f32_bf16_hi(h - bf16_to_f32(hb));
        }
    }

    f32x4 accm[8];
#pragma unroll
    for (int t = 0; t < 8; ++t) accm[t] = (f32x4)(0.f);
    const bf16x8* whp = (const bf16x8*)Whi;
    const bf16x8* wlp = (const bf16x8*)Wlo;
#pragma unroll
    for (int s = 0; s < 4; ++s) {
        const int base = (s * 8) * 64 + lane;
#pragma unroll
        for (int t = 0; t < 8; ++t) {
            bf16x8 wh = whp[base + t * 64];
            bf16x8 wl = wlp[base + t * 64];
            accm[t] = __builtin_amdgcn_mfma_f32_16x16x32_bf16(ahi[s], wh, accm[t], 0, 0, 0);
            accm[t] = __builtin_amdgcn_mfma_f32_16x16x32_bf16(alo[s], wh, accm[t], 0, 0, 0);
            accm[t] = __builtin_amdgcn_mfma_f32_16x16x32_bf16(ahi[s], wl, accm[t], 0, 0, 0);
        }
    }
#pragma unroll
    for (int r = 0; r < 4; ++r) {
        int row = row0 + q * 4 + r;
        if (row < N) {
#pragma unroll
            for (int t = 0; t < 8; ++t) {
                int c = t * 16 + m;
                float v = accm[t][r];
                if (c < 64) r16[(size_t)row * 64 + c] = __float2half(v);
                else        sarr[(size_t)row * 64 + (c - 64)] = v;
            }
        }
    }
}

// --------------- FUSED: agg2+softmax+gemm3 (K=64, dinv scale) --------------
__launch_bounds__(256)
__global__ void gcn_prep_fused_kernel(const __half* __restrict__ r16, const float* __restrict__ sarr,
                                      const int* __restrict__ rowptr, const int* __restrict__ col,
                                      const float* __restrict__ b2l,
                                      const unsigned short* __restrict__ Whi,
                                      const unsigned short* __restrict__ Wlo,
                                      const float* __restrict__ dinv,
                                      __half* __restrict__ tp16, int N) {
    const int lane = threadIdx.x & 63;
    const int wave = threadIdx.x >> 6;
    const int m = lane & 15, q = lane >> 4;
    const int row0 = blockIdx.x * 64 + wave * 16;
    int node = row0 + m;
    int nclamp = (node < N) ? node : (N - 1);
    int sIdx = rowptr[nclamp];
    int eIdx = (node < N) ? rowptr[nclamp + 1] : sIdx;

    float acc[2][8];
#pragma unroll
    for (int s = 0; s < 2; ++s)
#pragma unroll
        for (int i = 0; i < 8; ++i) acc[s][i] = 0.f;

    const __half* rb = r16 + q * 8;
    int ptr = sIdx;
    for (; ptr + 2 <= eIdx; ptr += 2) {
        int j0 = col[ptr], j1 = col[ptr + 1];
#pragma unroll
        for (int s = 0; s < 2; ++s) {
            H8 u0, u1;
            u0.f4 = *(const float4*)(rb + (size_t)j0 * 64 + s * 32);
            u1.f4 = *(const float4*)(rb + (size_t)j1 * 64 + s * 32);
#pragma unroll
            for (int k = 0; k < 4; ++k) {
                float2 f0 = __half22float2(u0.h[k]);
                float2 f1 = __half22float2(u1.h[k]);
                acc[s][2 * k]     += f0.x + f1.x;
                acc[s][2 * k + 1] += f0.y + f1.y;
            }
        }
    }
    if (ptr < eIdx) {
        int j0 = col[ptr];
#pragma unroll
        for (int s = 0; s < 2; ++s) {
            H8 u0;
            u0.f4 = *(const float4*)(rb + (size_t)j0 * 64 + s * 32);
#pragma unroll
            for (int k = 0; k < 4; ++k) {
                float2 f0 = __half22float2(u0.h[k]);
                acc[s][2 * k]     += f0.x;
                acc[s][2 * k + 1] += f0.y;
            }
        }
    }

    float inv = 1.0f / fmaxf((float)(eIdx - sIdx), 1.0f);
    float v[2][8];
    float mx = -1e30f;
#pragma unroll
    for (int s = 0; s < 2; ++s) {
        float sv[8], bv[8];
        *(float4*)(sv)     = *(const float4*)(sarr + (size_t)nclamp * 64 + s * 32 + q * 8);
        *(float4*)(sv + 4) = *(const float4*)(sarr + (size_t)nclamp * 64 + s * 32 + q * 8 + 4);
        *(float4*)(bv)     = *(const float4*)(b2l + s * 32 + q * 8);
        *(float4*)(bv + 4) = *(const float4*)(b2l + s * 32 + q * 8 + 4);
#pragma unroll
        for (int i = 0; i < 8; ++i) {
            v[s][i] = acc[s][i] * inv + sv[i] + bv[i];
            mx = fmaxf(mx, v[s][i]);
        }
    }
    mx = fmaxf(mx, __shfl_xor(mx, 16, 64));
    mx = fmaxf(mx, __shfl_xor(mx, 32, 64));
    float sm = 0.f;
#pragma unroll
    for (int s = 0; s < 2; ++s)
#pragma unroll
        for (int i = 0; i < 8; ++i) {
            v[s][i] = expf(v[s][i] - mx);
            sm += v[s][i];
        }
    sm += __shfl_xor(sm, 16, 64);
    sm += __shfl_xor(sm, 32, 64);
    float is = 1.0f / sm;

    bf16x8 ahi[2], alo[2];
#pragma unroll
    for (int s = 0; s < 2; ++s)
#pragma unroll
        for (int i = 0; i < 8; ++i) {
            float h = v[s][i] * is;
            unsigned short hb = f32_bf16_hi(h);
            ahi[s][i] = (short)hb;
            alo[s][i] = (short)f32_bf16_hi(h - bf16_to_f32(hb));
        }

    f32x4 accm[4];
#pragma unroll
    for (int t = 0; t < 4; ++t) accm[t] = (f32x4)(0.f);
    const bf16x8* whp = (const bf16x8*)Whi;
    const bf16x8* wlp = (const bf16x8*)Wlo;
#pragma unroll
    for (int s = 0; s < 2; ++s) {
        const int base = (s * 4) * 64 + lane;
#pragma unroll
        for (int t = 0; t < 4; ++t) {
            bf16x8 wh = whp[base + t * 64];
            bf16x8 wl = wlp[base + t * 64];
            accm[t] = __builtin_amdgcn_mfma_f32_16x16x32_bf16(ahi[s], wh, accm[t], 0, 0, 0);
            accm[t] = __builtin_amdgcn_mfma_f32_16x16x32_bf16(alo[s], wh, accm[t], 0, 0, 0);
            accm[t] = __builtin_amdgcn_mfma_f32_16x16x32_bf16(ahi[s], wl, accm[t], 0, 0, 0);
        }
    }
#pragma unroll
    for (int r = 0; r < 4; ++r) {
        int row = row0 + q * 4 + r;
        if (row < N) {
            float sc = dinv[row];
#pragma unroll
            for (int t = 0; t < 4; ++t) {
                int c = t * 16 + m;
                tp16[(size_t)row * 64 + c] = __float2half(accm[t][r] * sc);
            }
        }
    }
}

// ------------------------------ gcn gather ---------------------------------
__global__ void gcn_agg_kernel(const __half* __restrict__ tp,
                               const int* __restrict__ rowptr, const int* __restrict__ col,
                               const float* __restrict__ dinv, const float* __restrict__ bg,
                               float* __restrict__ out, int N) {
    int node = blockIdx.x * 4 + (threadIdx.x >> 6);
    if (node >= N) return;
    int lane = threadIdx.x & 63;
    int s = rowptr[node], e = rowptr[node + 1];
    float a[8];
#pragma unroll
    for (int k = 0; k < 8; ++k) a[k] = 0.f;
    int p = s;
    for (; p + 8 <= e; p += 8) {
#pragma unroll
        for (int k = 0; k < 8; ++k)
            a[k] += __half2float(tp[(size_t)col[p + k] * 64 + lane]);
    }
    for (; p < e; ++p) a[0] += __half2float(tp[(size_t)col[p] * 64 + lane]);
    float acc = ((a[0] + a[1]) + (a[2] + a[3])) + ((a[4] + a[5]) + (a[6] + a[7]));
    float di = dinv[node];
    out[(size_t)node * 64 + lane] =
        (acc + __half2float(tp[(size_t)node * 64 + lane])) * di + bg[lane];
}

extern "C" void kernel_launch(void* const* d_in, const int* in_sizes, int n_in,
                              void* d_out, int out_size, void* d_ws, size_t ws_size,
                              hipStream_t stream) {
    const float* x = (const float*)d_in[0];
    const int* ei = (const int*)d_in[1];    // int32 per harness conversion
    const float* W1l = (const float*)d_in[2];
    const float* b1l = (const float*)d_in[3];
    const float* W1r = (const float*)d_in[4];
    const float* W2l = (const float*)d_in[5];
    const float* b2l = (const float*)d_in[6];
    const float* W2r = (const float*)d_in[7];
    const float* Wg  = (const float*)d_in[8];
    const float* bg  = (const float*)d_in[9];

    const int N = in_sizes[0] / 128;
    const int E = in_sizes[1] / 2;
    const int* srcp = ei;
    const int* dstp = ei + E;

    const int NB = (E + 8191) / 8192;
    const int BK = (N + 255) >> 8;
    const int len = BK * NB;

    // workspace layout
    float* ws = (float*)d_ws;
    float* q    = ws;                          // N*128 fp32
    float* sarr = q + (size_t)N * 128;         // N*64 fp32
    float* dinv = sarr + (size_t)N * 64;       // N
    __half* p16 = (__half*)(dinv + N);         // N*128 half
    __half* r16 = p16 + (size_t)N * 128;       // N*64 half
    __half* tp16 = r16 + (size_t)N * 64;       // N*64 half
    int* rowptr = (int*)(tp16 + (size_t)N * 64); // N+1
    int* off    = rowptr + (N + 1);            // len+2
    int* colbuf = off + len + 2;               // E
    unsigned* ebuf = (unsigned*)(colbuf + E);  // E
    int* bsum   = (int*)(ebuf + E);            // 32
    uintptr_t up = (uintptr_t)(bsum + 32);
    up = (up + 15) & ~(uintptr_t)15;
    unsigned short* p1h = (unsigned short*)up; // 32768 (128x256)
    unsigned short* p1l = p1h + 32768;
    unsigned short* p2h = p1l + 32768;         // 16384 (128x128)
    unsigned short* p2l = p2h + 16384;
    unsigned short* p3h = p2l + 16384;         // 4096 (64x64)
    unsigned short* p3l = p3h + 4096;

    float* out = (float*)d_out;

    // --- CSR build (radix by dst) ---
    count_kernel<<<NB, 256, 0, stream>>>(dstp, off, E, NB, BK);
    const int sn = len + 1;
    const int SBs = (sn + 2047) / 2048;
    scan_reduce_kernel<<<SBs, 256, 0, stream>>>(off, bsum, sn);
    scan_offsets_kernel<<<1, 64, 0, stream>>>(bsum, SBs);
    scan_final_kernel<<<SBs, 256, 0, stream>>>(off, bsum, sn);
    partition_kernel<<<NB, 256, 0, stream>>>(srcp, dstp, off, ebuf, E, NB, BK);
    finalize_kernel<<<BK, 256, 0, stream>>>(ebuf, off, colbuf, rowptr, dinv, N, NB, E);

    packw_kernel<<<dim3(64, 5), 256, 0, stream>>>(W1l, W1r, W2l, W2r, Wg,
                                                  p1h, p1l, p2h, p2l, p3h, p3l);

    const int gb = (N + 63) / 64;
    const int ab = (N + 3) / 4;

    // gemm1: Ttot=16 tiles, 2 blocks of 8 (y=0 -> p16 cols, y=1 -> q cols)
    gemm_mfma_kernel<128, 16, 8, true, true><<<dim3(gb, 2), 256, 0, stream>>>(
        x, p1h, p1l, (void*)p16, q, nullptr, N);

    // fused: h1 = relu(mean(p16)+q+b1l); [r16|sarr] = h1 @ [W2l|W2r]
    sage2_fused_kernel<<<gb, 256, 0, stream>>>(p16, q, rowptr, colbuf, b1l,
                                               p2h, p2l, r16, sarr, N);

    // fused: h2 = softmax(mean(r16)+sarr+b2l); tp16 = (h2 @ Wg) * dinv
    gcn_prep_fused_kernel<<<gb, 256, 0, stream>>>(r16, sarr, rowptr, colbuf, b2l,
                                                  p3h, p3l, dinv, tp16, N);

    gcn_agg_kernel<<<ab, 256, 0, stream>>>(tp16, rowptr, colbuf, dinv, bg, out, N);
}

// Round 13
// 300.409 us; speedup vs baseline: 1.0834x; 1.0184x over previous
//
#include <hip/hip_runtime.h>
#include <hip/hip_fp16.h>
#include <math.h>

// ---------------------------------------------------------------------------
// ADSAGE: 2x SAGEConv (mean aggr) + softmax + GCNConv, fp32.
// Aggregate-after-GEMM (mean is linear). GEMMs on matrix cores via
// split-bf16 (3-term). CSR via 2-pass radix sort by dst. Gathered
// activations (p16, r16, tp16) stored FP16. Register-resident fusion: the
// gather phase assigns lane (m,q) to features q*8+32s of node row0+m, which
// IS the MFMA A-fragment layout -> gather + epilogue + GEMM in one kernel,
// no LDS, no barrier, no h1/h2 global round trip. Edge loops unrolled x4
// (16 outstanding 16B loads/lane in sage2) to push the latency-bound gather.
// Pipeline:
//   p16,q = x @ [W1l|W1r]                        MFMA GEMM K=128 (p fp16)
//   r16,s = relu(mean(p16)+q+b1l) @ [W2l|W2r]    FUSED gather+GEMM K=128
//   tp16  = softmax(mean(r16)+s+b2l) @ Wg * dinv FUSED gather+softmax+GEMM
//   out   = dinv*(sum_j tp[j] + tp[i]) + bg      gather (fp16 in, fp32 out)
// ---------------------------------------------------------------------------

typedef __attribute__((ext_vector_type(8))) short bf16x8;
typedef __attribute__((ext_vector_type(4))) float f32x4;

__device__ inline unsigned short f32_bf16_hi(float f) {
    unsigned int u = __builtin_bit_cast(unsigned int, f);
    u = (u + 0x7FFFu + ((u >> 16) & 1u)) >> 16;
    return (unsigned short)u;
}
__device__ inline float bf16_to_f32(unsigned short h) {
    unsigned int u = ((unsigned int)h) << 16;
    return __builtin_bit_cast(float, u);
}

union H8 { float4 f4; __half2 h[4]; };

// ----------------------- radix CSR build (by dst) --------------------------
__global__ void count_kernel(const int* __restrict__ dst, int* __restrict__ off,
                             int E, int NB, int BK) {
    __shared__ int hist[256];
    int t = threadIdx.x;
    hist[t] = 0;
    __syncthreads();
    int base = blockIdx.x * 8192;
    for (int i = t; i < 8192; i += 256) {
        int e = base + i;
        if (e < E) atomicAdd(&hist[dst[e] >> 8], 1);
    }
    __syncthreads();
    if (t < BK) off[1 + t * NB + blockIdx.x] = hist[t];
    if (blockIdx.x == 0 && t == 0) off[0] = 0;
}

__global__ void scan_reduce_kernel(const int* __restrict__ data, int* __restrict__ bsum, int n) {
    __shared__ int red[256];
    int t = threadIdx.x;
    int base = blockIdx.x * 2048 + t * 8;
    int s = 0;
    if (base + 8 <= n) {
        int4 a = *(const int4*)(data + base);
        int4 b = *(const int4*)(data + base + 4);
        s = a.x + a.y + a.z + a.w + b.x + b.y + b.z + b.w;
    } else {
        for (int i = 0; i < 8; ++i)
            if (base + i < n) s += data[base + i];
    }
    red[t] = s;
    __syncthreads();
    for (int off = 128; off > 0; off >>= 1) {
        if (t < off) red[t] += red[t + off];
        __syncthreads();
    }
    if (t == 0) bsum[blockIdx.x] = red[0];
}

__global__ void scan_offsets_kernel(int* __restrict__ bsum, int B) {
    if (threadIdx.x == 0 && blockIdx.x == 0) {
        int run = 0;
        for (int i = 0; i < B; ++i) { int v = bsum[i]; bsum[i] = run; run += v; }
    }
}

__global__ void scan_final_kernel(int* __restrict__ data, const int* __restrict__ bsum, int n) {
    __shared__ int tsum[256];
    int t = threadIdx.x;
    int base = blockIdx.x * 2048 + t * 8;
    int v[8];
    int s = 0;
#pragma unroll
    for (int i = 0; i < 8; ++i) {
        v[i] = (base + i < n) ? data[base + i] : 0;
        s += v[i];
    }
    tsum[t] = s;
    for (int off = 1; off < 256; off <<= 1) {
        __syncthreads();
        int u = (t >= off) ? tsum[t - off] : 0;
        __syncthreads();
        tsum[t] += u;
    }
    __syncthreads();
    int run = bsum[blockIdx.x] + tsum[t] - s;
#pragma unroll
    for (int i = 0; i < 8; ++i) {
        run += v[i];
        if (base + i < n) data[base + i] = run;
    }
}

__global__ void partition_kernel(const int* __restrict__ src, const int* __restrict__ dst,
                                 const int* __restrict__ off, unsigned* __restrict__ ebuf,
                                 int E, int NB, int BK) {
    __shared__ int cur[256];
    int t = threadIdx.x;
    if (t < BK) cur[t] = off[t * NB + blockIdx.x];
    __syncthreads();
    int base = blockIdx.x * 8192;
    for (int i = t; i < 8192; i += 256) {
        int e = base + i;
        if (e < E) {
            int d = dst[e];
            int pos = atomicAdd(&cur[d >> 8], 1);
            ebuf[pos] = ((unsigned)src[e] << 8) | (unsigned)(d & 255);
        }
    }
}

__global__ void finalize_kernel(const unsigned* __restrict__ ebuf, const int* __restrict__ off,
                                int* __restrict__ col, int* __restrict__ rowptr,
                                float* __restrict__ dinv, int N, int NB, int E) {
    __shared__ int hist[256], scn[256], cur[256];
    int b = blockIdx.x, t = threadIdx.x;
    int base = off[b * NB];
    int end  = off[(b + 1) * NB];
    int M = end - base;
    hist[t] = 0;
    __syncthreads();
    for (int i = t; i < M; i += 256) atomicAdd(&hist[ebuf[base + i] & 255u], 1);
    __syncthreads();
    scn[t] = hist[t];
    for (int o = 1; o < 256; o <<= 1) {
        __syncthreads();
        int u = (t >= o) ? scn[t - o] : 0;
        __syncthreads();
        scn[t] += u;
    }
    __syncthreads();
    int excl = scn[t] - hist[t];
    int node = b * 256 + t;
    if (node < N) {
        rowptr[node] = base + excl;
        dinv[node] = rsqrtf((float)(hist[t] + 1));
    }
    if (b == 0 && t == 0) rowptr[N] = E;
    cur[t] = base + excl;
    __syncthreads();
    for (int i = t; i < M; i += 256) {
        unsigned w = ebuf[base + i];
        int pos = atomicAdd(&cur[w & 255u], 1);
        col[pos] = (int)(w >> 8);
    }
}

// -------------------------- weight pre-pack --------------------------------
__global__ void packw_kernel(const float* __restrict__ W1l, const float* __restrict__ W1r,
                             const float* __restrict__ W2l, const float* __restrict__ W2r,
                             const float* __restrict__ Wg,
                             unsigned short* __restrict__ p1h, unsigned short* __restrict__ p1l,
                             unsigned short* __restrict__ p2h, unsigned short* __restrict__ p2l,
                             unsigned short* __restrict__ p3h, unsigned short* __restrict__ p3l) {
    int which = blockIdx.y;
    const float* W;
    unsigned short *hi, *lo;
    int K, Mp, colOff, T;
    if (which == 0)      { W = W1l; hi = p1h; lo = p1l; K = 128; Mp = 128; colOff = 0;   T = 16; }
    else if (which == 1) { W = W1r; hi = p1h; lo = p1l; K = 128; Mp = 128; colOff = 128; T = 16; }
    else if (which == 2) { W = W2l; hi = p2h; lo = p2l; K = 128; Mp = 64;  colOff = 0;   T = 8;  }
    else if (which == 3) { W = W2r; hi = p2h; lo = p2l; K = 128; Mp = 64;  colOff = 64;  T = 8;  }
    else                 { W = Wg;  hi = p3h; lo = p3l; K = 64;  Mp = 64;  colOff = 0;   T = 4;  }
    int idx = blockIdx.x * blockDim.x + threadIdx.x;
    if (idx >= K * Mp) return;
    int k = idx / Mp, m = idx % Mp;
    float w = W[(size_t)k * Mp + m];
    int colI = colOff + m;
    int s = k >> 5, kk = k & 31, qq = kk >> 3, j = kk & 7;
    int tt = colI >> 4, n = colI & 15;
    int lane = qq * 16 + n;
    size_t pos = ((size_t)(s * T + tt) * 64 + lane) * 8 + j;
    unsigned short h = f32_bf16_hi(w);
    hi[pos] = h;
    lo[pos] = f32_bf16_hi(w - bf16_to_f32(h));
}

// --------------------------- MFMA GEMM (gemm1) -----------------------------
template <int K, int Ttot, int TB, bool SPLIT, bool A16>
__launch_bounds__(256)
__global__ void gemm_mfma_kernel(const float* __restrict__ A,
                                 const unsigned short* __restrict__ Whi,
                                 const unsigned short* __restrict__ Wlo,
                                 void* __restrict__ outAv, float* __restrict__ outB,
                                 const float* __restrict__ rowScale, int N) {
    constexpr int S = K / 32, M = Ttot * 16, H = SPLIT ? M / 2 : M;
    const int lane = threadIdx.x & 63;
    const int wave = threadIdx.x >> 6;
    const int m = lane & 15, q = lane >> 4;
    const int t0 = blockIdx.y * TB;
    const int row0 = blockIdx.x * 64 + wave * 16;
    int arow = row0 + m;
    if (arow >= N) arow = N - 1;
    const float* ap = A + (size_t)arow * K + q * 8;

    f32x4 acc[TB];
#pragma unroll
    for (int t = 0; t < TB; ++t) acc[t] = (f32x4)(0.f);

#pragma unroll
    for (int s = 0; s < S; ++s) {
        float av[8];
        *(float4*)(av)     = *(const float4*)(ap + s * 32);
        *(float4*)(av + 4) = *(const float4*)(ap + s * 32 + 4);
        bf16x8 ahi, alo;
#pragma unroll
        for (int i = 0; i < 8; ++i) {
            unsigned short h = f32_bf16_hi(av[i]);
            ahi[i] = (short)h;
            alo[i] = (short)f32_bf16_hi(av[i] - bf16_to_f32(h));
        }
        const int base = (s * Ttot + t0) * 64 + lane;
        const bf16x8* whp = (const bf16x8*)Whi;
        const bf16x8* wlp = (const bf16x8*)Wlo;
#pragma unroll
        for (int t = 0; t < TB; ++t) {
            bf16x8 wh = whp[base + t * 64];
            bf16x8 wl = wlp[base + t * 64];
            acc[t] = __builtin_amdgcn_mfma_f32_16x16x32_bf16(ahi, wh, acc[t], 0, 0, 0);
            acc[t] = __builtin_amdgcn_mfma_f32_16x16x32_bf16(alo, wh, acc[t], 0, 0, 0);
            acc[t] = __builtin_amdgcn_mfma_f32_16x16x32_bf16(ahi, wl, acc[t], 0, 0, 0);
        }
    }

#pragma unroll
    for (int r = 0; r < 4; ++r) {
        int row = row0 + q * 4 + r;
        if (row < N) {
            float sc = rowScale ? rowScale[row] : 1.0f;
#pragma unroll
            for (int t = 0; t < TB; ++t) {
                int c = (t0 + t) * 16 + m;
                float v = acc[t][r] * sc;
                if (c < H) {
                    if (A16) ((__half*)outAv)[(size_t)row * H + c] = __float2half(v);
                    else     ((float*)outAv)[(size_t)row * H + c] = v;
                } else {
                    outB[(size_t)row * (M - H) + (c - H)] = v;
                }
            }
        }
    }
}

// ------------------- FUSED: agg1+relu+gemm2 (K=128) ------------------------
// Lane (m,q) gathers feats [s*32+q*8 .. +7] (s=0..3) of node row0+m directly
// into MFMA A-fragment layout. Edge loop x4: 16 float4 loads in flight.
__launch_bounds__(256)
__global__ void sage2_fused_kernel(const __half* __restrict__ p16, const float* __restrict__ qarr,
                                   const int* __restrict__ rowptr, const int* __restrict__ col,
                                   const float* __restrict__ b1l,
                                   const unsigned short* __restrict__ Whi,
                                   const unsigned short* __restrict__ Wlo,
                                   __half* __restrict__ r16, float* __restrict__ sarr, int N) {
    const int lane = threadIdx.x & 63;
    const int wave = threadIdx.x >> 6;
    const int m = lane & 15, q = lane >> 4;
    const int row0 = blockIdx.x * 64 + wave * 16;
    int node = row0 + m;
    int nclamp = (node < N) ? node : (N - 1);
    int sIdx = rowptr[nclamp];
    int eIdx = (node < N) ? rowptr[nclamp + 1] : sIdx;

    float acc[4][8];
#pragma unroll
    for (int s = 0; s < 4; ++s)
#pragma unroll
        for (int i = 0; i < 8; ++i) acc[s][i] = 0.f;

    const __half* pb = p16 + q * 8;
    int ptr = sIdx;
    for (; ptr + 4 <= eIdx; ptr += 4) {
        int j0 = col[ptr], j1 = col[ptr + 1], j2 = col[ptr + 2], j3 = col[ptr + 3];
        H8 u[4][4];   // [edge][s] — all 16 loads independent, issued together
#pragma unroll
        for (int s = 0; s < 4; ++s) {
            u[0][s].f4 = *(const float4*)(pb + (size_t)j0 * 128 + s * 32);
            u[1][s].f4 = *(const float4*)(pb + (size_t)j1 * 128 + s * 32);
            u[2][s].f4 = *(const float4*)(pb + (size_t)j2 * 128 + s * 32);
            u[3][s].f4 = *(const float4*)(pb + (size_t)j3 * 128 + s * 32);
        }
#pragma unroll
        for (int s = 0; s < 4; ++s)
#pragma unroll
            for (int k = 0; k < 4; ++k) {
                float2 f0 = __half22float2(u[0][s].h[k]);
                float2 f1 = __half22float2(u[1][s].h[k]);
                float2 f2 = __half22float2(u[2][s].h[k]);
                float2 f3 = __half22float2(u[3][s].h[k]);
                acc[s][2 * k]     += (f0.x + f1.x) + (f2.x + f3.x);
                acc[s][2 * k + 1] += (f0.y + f1.y) + (f2.y + f3.y);
            }
    }
    for (; ptr < eIdx; ++ptr) {
        int j0 = col[ptr];
#pragma unroll
        for (int s = 0; s < 4; ++s) {
            H8 u0;
            u0.f4 = *(const float4*)(pb + (size_t)j0 * 128 + s * 32);
#pragma unroll
            for (int k = 0; k < 4; ++k) {
                float2 f0 = __half22float2(u0.h[k]);
                acc[s][2 * k]     += f0.x;
                acc[s][2 * k + 1] += f0.y;
            }
        }
    }

    float inv = 1.0f / fmaxf((float)(eIdx - sIdx), 1.0f);
    bf16x8 ahi[4], alo[4];
#pragma unroll
    for (int s = 0; s < 4; ++s) {
        float qv[8], bv[8];
        *(float4*)(qv)     = *(const float4*)(qarr + (size_t)nclamp * 128 + s * 32 + q * 8);
        *(float4*)(qv + 4) = *(const float4*)(qarr + (size_t)nclamp * 128 + s * 32 + q * 8 + 4);
        *(float4*)(bv)     = *(const float4*)(b1l + s * 32 + q * 8);
        *(float4*)(bv + 4) = *(const float4*)(b1l + s * 32 + q * 8 + 4);
#pragma unroll
        for (int i = 0; i < 8; ++i) {
            float h = fmaxf(acc[s][i] * inv + qv[i] + bv[i], 0.f);
            unsigned short hb = f32_bf16_hi(h);
            ahi[s][i] = (short)hb;
            alo[s][i] = (short)f32_bf16_hi(h - bf16_to_f32(hb));
        }
    }

    f32x4 accm[8];
#pragma unroll
    for (int t = 0; t < 8; ++t) accm[t] = (f32x4)(0.f);
    const bf16x8* whp = (const bf16x8*)Whi;
    const bf16x8* wlp = (const bf16x8*)Wlo;
#pragma unroll
    for (int s = 0; s < 4; ++s) {
        const int base = (s * 8) * 64 + lane;
#pragma unroll
        for (int t = 0; t < 8; ++t) {
            bf16x8 wh = whp[base + t * 64];
            bf16x8 wl = wlp[base + t * 64];
            accm[t] = __builtin_amdgcn_mfma_f32_16x16x32_bf16(ahi[s], wh, accm[t], 0, 0, 0);
            accm[t] = __builtin_amdgcn_mfma_f32_16x16x32_bf16(alo[s], wh, accm[t], 0, 0, 0);
            accm[t] = __builtin_amdgcn_mfma_f32_16x16x32_bf16(ahi[s], wl, accm[t], 0, 0, 0);
        }
    }
#pragma unroll
    for (int r = 0; r < 4; ++r) {
        int row = row0 + q * 4 + r;
        if (row < N) {
#pragma unroll
            for (int t = 0; t < 8; ++t) {
                int c = t * 16 + m;
                float v = accm[t][r];
                if (c < 64) r16[(size_t)row * 64 + c] = __float2half(v);
                else        sarr[(size_t)row * 64 + (c - 64)] = v;
            }
        }
    }
}

// --------------- FUSED: agg2+softmax+gemm3 (K=64, dinv scale) --------------
__launch_bounds__(256)
__global__ void gcn_prep_fused_kernel(const __half* __restrict__ r16, const float* __restrict__ sarr,
                                      const int* __restrict__ rowptr, const int* __restrict__ col,
                                      const float* __restrict__ b2l,
                                      const unsigned short* __restrict__ Whi,
                                      const unsigned short* __restrict__ Wlo,
                                      const float* __restrict__ dinv,
                                      __half* __restrict__ tp16, int N) {
    const int lane = threadIdx.x & 63;
    const int wave = threadIdx.x >> 6;
    const int m = lane & 15, q = lane >> 4;
    const int row0 = blockIdx.x * 64 + wave * 16;
    int node = row0 + m;
    int nclamp = (node < N) ? node : (N - 1);
    int sIdx = rowptr[nclamp];
    int eIdx = (node < N) ? rowptr[nclamp + 1] : sIdx;

    float acc[2][8];
#pragma unroll
    for (int s = 0; s < 2; ++s)
#pragma unroll
        for (int i = 0; i < 8; ++i) acc[s][i] = 0.f;

    const __half* rb = r16 + q * 8;
    int ptr = sIdx;
    for (; ptr + 4 <= eIdx; ptr += 4) {
        int j0 = col[ptr], j1 = col[ptr + 1], j2 = col[ptr + 2], j3 = col[ptr + 3];
        H8 u[4][2];
#pragma unroll
        for (int s = 0; s < 2; ++s) {
            u[0][s].f4 = *(const float4*)(rb + (size_t)j0 * 64 + s * 32);
            u[1][s].f4 = *(const float4*)(rb + (size_t)j1 * 64 + s * 32);
            u[2][s].f4 = *(const float4*)(rb + (size_t)j2 * 64 + s * 32);
            u[3][s].f4 = *(const float4*)(rb + (size_t)j3 * 64 + s * 32);
        }
#pragma unroll
        for (int s = 0; s < 2; ++s)
#pragma unroll
            for (int k = 0; k < 4; ++k) {
                float2 f0 = __half22float2(u[0][s].h[k]);
                float2 f1 = __half22float2(u[1][s].h[k]);
                float2 f2 = __half22float2(u[2][s].h[k]);
                float2 f3 = __half22float2(u[3][s].h[k]);
                acc[s][2 * k]     += (f0.x + f1.x) + (f2.x + f3.x);
                acc[s][2 * k + 1] += (f0.y + f1.y) + (f2.y + f3.y);
            }
    }
    for (; ptr < eIdx; ++ptr) {
        int j0 = col[ptr];
#pragma unroll
        for (int s = 0; s < 2; ++s) {
            H8 u0;
            u0.f4 = *(const float4*)(rb + (size_t)j0 * 64 + s * 32);
#pragma unroll
            for (int k = 0; k < 4; ++k) {
                float2 f0 = __half22float2(u0.h[k]);
                acc[s][2 * k]     += f0.x;
                acc[s][2 * k + 1] += f0.y;
            }
        }
    }

    float inv = 1.0f / fmaxf((float)(eIdx - sIdx), 1.0f);
    float v[2][8];
    float mx = -1e30f;
#pragma unroll
    for (int s = 0; s < 2; ++s) {
        float sv[8], bv[8];
        *(float4*)(sv)     = *(const float4*)(sarr + (size_t)nclamp * 64 + s * 32 + q * 8);
        *(float4*)(sv + 4) = *(const float4*)(sarr + (size_t)nclamp * 64 + s * 32 + q * 8 + 4);
        *(float4*)(bv)     = *(const float4*)(b2l + s * 32 + q * 8);
        *(float4*)(bv + 4) = *(const float4*)(b2l + s * 32 + q * 8 + 4);
#pragma unroll
        for (int i = 0; i < 8; ++i) {
            v[s][i] = acc[s][i] * inv + sv[i] + bv[i];
            mx = fmaxf(mx, v[s][i]);
        }
    }
    mx = fmaxf(mx, __shfl_xor(mx, 16, 64));
    mx = fmaxf(mx, __shfl_xor(mx, 32, 64));
    float sm = 0.f;
#pragma unroll
    for (int s = 0; s < 2; ++s)
#pragma unroll
        for (int i = 0; i < 8; ++i) {
            v[s][i] = expf(v[s][i] - mx);
            sm += v[s][i];
        }
    sm += __shfl_xor(sm, 16, 64);
    sm += __shfl_xor(sm, 32, 64);
    float is = 1.0f / sm;

    bf16x8 ahi[2], alo[2];
#pragma unroll
    for (int s = 0; s < 2; ++s)
#pragma unroll
        for (int i = 0; i < 8; ++i) {
            float h = v[s][i] * is;
            unsigned short hb = f32_bf16_hi(h);
            ahi[s][i] = (short)hb;
            alo[s][i] = (short)f32_bf16_hi(h - bf16_to_f32(hb));
        }

    f32x4 accm[4];
#pragma unroll
    for (int t = 0; t < 4; ++t) accm[t] = (f32x4)(0.f);
    const bf16x8* whp = (const bf16x8*)Whi;
    const bf16x8* wlp = (const bf16x8*)Wlo;
#pragma unroll
    for (int s = 0; s < 2; ++s) {
        const int base = (s * 4) * 64 + lane;
#pragma unroll
        for (int t = 0; t < 4; ++t) {
            bf16x8 wh = whp[base + t * 64];
            bf16x8 wl = wlp[base + t * 64];
            accm[t] = __builtin_amdgcn_mfma_f32_16x16x32_bf16(ahi[s], wh, accm[t], 0, 0, 0);
            accm[t] = __builtin_amdgcn_mfma_f32_16x16x32_bf16(alo[s], wh, accm[t], 0, 0, 0);
            accm[t] = __builtin_amdgcn_mfma_f32_16x16x32_bf16(ahi[s], wl, accm[t], 0, 0, 0);
        }
    }
#pragma unroll
    for (int r = 0; r < 4; ++r) {
        int row = row0 + q * 4 + r;
        if (row < N) {
            float sc = dinv[row];
#pragma unroll
            for (int t = 0; t < 4; ++t) {
                int c = t * 16 + m;
                tp16[(size_t)row * 64 + c] = __float2half(accm[t][r] * sc);
            }
        }
    }
}

// ------------------------------ gcn gather ---------------------------------
__global__ void gcn_agg_kernel(const __half* __restrict__ tp,
                               const int* __restrict__ rowptr, const int* __restrict__ col,
                               const float* __restrict__ dinv, const float* __restrict__ bg,
                               float* __restrict__ out, int N) {
    int node = blockIdx.x * 4 + (threadIdx.x >> 6);
    if (node >= N) return;
    int lane = threadIdx.x & 63;
    int s = rowptr[node], e = rowptr[node + 1];
    float a[8];
#pragma unroll
    for (int k = 0; k < 8; ++k) a[k] = 0.f;
    int p = s;
    for (; p + 8 <= e; p += 8) {
#pragma unroll
        for (int k = 0; k < 8; ++k)
            a[k] += __half2float(tp[(size_t)col[p + k] * 64 + lane]);
    }
    for (; p < e; ++p) a[0] += __half2float(tp[(size_t)col[p] * 64 + lane]);
    float acc = ((a[0] + a[1]) + (a[2] + a[3])) + ((a[4] + a[5]) + (a[6] + a[7]));
    float di = dinv[node];
    out[(size_t)node * 64 + lane] =
        (acc + __half2float(tp[(size_t)node * 64 + lane])) * di + bg[lane];
}

extern "C" void kernel_launch(void* const* d_in, const int* in_sizes, int n_in,
                              void* d_out, int out_size, void* d_ws, size_t ws_size,
                              hipStream_t stream) {
    const float* x = (const float*)d_in[0];
    const int* ei = (const int*)d_in[1];    // int32 per harness conversion
    const float* W1l = (const float*)d_in[2];
    const float* b1l = (const float*)d_in[3];
    const float* W1r = (const float*)d_in[4];
    const float* W2l = (const float*)d_in[5];
    const float* b2l = (const float*)d_in[6];
    const float* W2r = (const float*)d_in[7];
    const float* Wg  = (const float*)d_in[8];
    const float* bg  = (const float*)d_in[9];

    const int N = in_sizes[0] / 128;
    const int E = in_sizes[1] / 2;
    const int* srcp = ei;
    const int* dstp = ei + E;

    const int NB = (E + 8191) / 8192;
    const int BK = (N + 255) >> 8;
    const int len = BK * NB;

    // workspace layout
    float* ws = (float*)d_ws;
    float* q    = ws;                          // N*128 fp32
    float* sarr = q + (size_t)N * 128;         // N*64 fp32
    float* dinv = sarr + (size_t)N * 64;       // N
    __half* p16 = (__half*)(dinv + N);         // N*128 half
    __half* r16 = p16 + (size_t)N * 128;       // N*64 half
    __half* tp16 = r16 + (size_t)N * 64;       // N*64 half
    int* rowptr = (int*)(tp16 + (size_t)N * 64); // N+1
    int* off    = rowptr + (N + 1);            // len+2
    int* colbuf = off + len + 2;               // E
    unsigned* ebuf = (unsigned*)(colbuf + E);  // E
    int* bsum   = (int*)(ebuf + E);            // 32
    uintptr_t up = (uintptr_t)(bsum + 32);
    up = (up + 15) & ~(uintptr_t)15;
    unsigned short* p1h = (unsigned short*)up; // 32768 (128x256)
    unsigned short* p1l = p1h + 32768;
    unsigned short* p2h = p1l + 32768;         // 16384 (128x128)
    unsigned short* p2l = p2h + 16384;
    unsigned short* p3h = p2l + 16384;         // 4096 (64x64)
    unsigned short* p3l = p3h + 4096;

    float* out = (float*)d_out;

    // --- CSR build (radix by dst) ---
    count_kernel<<<NB, 256, 0, stream>>>(dstp, off, E, NB, BK);
    const int sn = len + 1;
    const int SBs = (sn + 2047) / 2048;
    scan_reduce_kernel<<<SBs, 256, 0, stream>>>(off, bsum, sn);
    scan_offsets_kernel<<<1, 64, 0, stream>>>(bsum, SBs);
    scan_final_kernel<<<SBs, 256, 0, stream>>>(off, bsum, sn);
    partition_kernel<<<NB, 256, 0, stream>>>(srcp, dstp, off, ebuf, E, NB, BK);
    finalize_kernel<<<BK, 256, 0, stream>>>(ebuf, off, colbuf, rowptr, dinv, N, NB, E);

    packw_kernel<<<dim3(64, 5), 256, 0, stream>>>(W1l, W1r, W2l, W2r, Wg,
                                                  p1h, p1l, p2h, p2l, p3h, p3l);

    const int gb = (N + 63) / 64;
    const int ab = (N + 3) / 4;

    // gemm1: Ttot=16 tiles, 2 blocks of 8 (y=0 -> p16 cols, y=1 -> q cols)
    gemm_mfma_kernel<128, 16, 8, true, true><<<dim3(gb, 2), 256, 0, stream>>>(
        x, p1h, p1l, (void*)p16, q, nullptr, N);

    // fused: h1 = relu(mean(p16)+q+b1l); [r16|sarr] = h1 @ [W2l|W2r]
    sage2_fused_kernel<<<gb, 256, 0, stream>>>(p16, q, rowptr, colbuf, b1l,
                                               p2h, p2l, r16, sarr, N);

    // fused: h2 = softmax(mean(r16)+sarr+b2l); tp16 = (h2 @ Wg) * dinv
    gcn_prep_fused_kernel<<<gb, 256, 0, stream>>>(r16, sarr, rowptr, colbuf, b2l,
                                                  p3h, p3l, dinv, tp16, N);

    gcn_agg_kernel<<<ab, 256, 0, stream>>>(tp16, rowptr, colbuf, dinv, bg, out, N);
}

// Round 14
// 285.547 us; speedup vs baseline: 1.1398x; 1.0520x over previous
//
#include <hip/hip_runtime.h>
#include <hip/hip_fp16.h>
#include <math.h>

// ---------------------------------------------------------------------------
// ADSAGE: 2x SAGEConv (mean aggr) + softmax + GCNConv, fp32.
// Aggregate-after-GEMM (mean is linear). GEMMs on matrix cores via
// split-bf16 (3-term). CSR via 2-pass radix sort by dst. ALL intermediate
// activations (p16, q16, r16, s16, tp16) stored FP16. Register-resident
// fusion: gather lands directly in MFMA A-fragment layout (lane (m,q) owns
// feats q*8+32s of node row0+m) -> gather+epilogue+GEMM in one kernel.
// gemm1 hoists all A loads before the MFMA chain (was 46us latency-bound on
// 4 serialized HBM loads/wave).
// Pipeline:
//   p16,q16 = x @ [W1l|W1r]                      gemm1 (A-loads hoisted)
//   r16,s16 = relu(mean(p16)+q16+b1l) @ [W2l|W2r]  FUSED gather+GEMM K=128
//   tp16  = softmax(mean(r16)+s16+b2l) @ Wg * dinv FUSED gather+softmax+GEMM
//   out   = dinv*(sum_j tp[j] + tp[i]) + bg        gather (fp16 in, fp32 out)
// ---------------------------------------------------------------------------

typedef __attribute__((ext_vector_type(8))) short bf16x8;
typedef __attribute__((ext_vector_type(4))) float f32x4;

__device__ inline unsigned short f32_bf16_hi(float f) {
    unsigned int u = __builtin_bit_cast(unsigned int, f);
    u = (u + 0x7FFFu + ((u >> 16) & 1u)) >> 16;
    return (unsigned short)u;
}
__device__ inline float bf16_to_f32(unsigned short h) {
    unsigned int u = ((unsigned int)h) << 16;
    return __builtin_bit_cast(float, u);
}

union H8 { float4 f4; __half2 h[4]; };

// ----------------------- radix CSR build (by dst) --------------------------
__global__ void count_kernel(const int* __restrict__ dst, int* __restrict__ off,
                             int E, int NB, int BK) {
    __shared__ int hist[256];
    int t = threadIdx.x;
    hist[t] = 0;
    __syncthreads();
    int base = blockIdx.x * 8192;
    for (int i = t; i < 8192; i += 256) {
        int e = base + i;
        if (e < E) atomicAdd(&hist[dst[e] >> 8], 1);
    }
    __syncthreads();
    if (t < BK) off[1 + t * NB + blockIdx.x] = hist[t];
    if (blockIdx.x == 0 && t == 0) off[0] = 0;
}

__global__ void scan_reduce_kernel(const int* __restrict__ data, int* __restrict__ bsum, int n) {
    __shared__ int red[256];
    int t = threadIdx.x;
    int base = blockIdx.x * 2048 + t * 8;
    int s = 0;
    if (base + 8 <= n) {
        int4 a = *(const int4*)(data + base);
        int4 b = *(const int4*)(data + base + 4);
        s = a.x + a.y + a.z + a.w + b.x + b.y + b.z + b.w;
    } else {
        for (int i = 0; i < 8; ++i)
            if (base + i < n) s += data[base + i];
    }
    red[t] = s;
    __syncthreads();
    for (int off = 128; off > 0; off >>= 1) {
        if (t < off) red[t] += red[t + off];
        __syncthreads();
    }
    if (t == 0) bsum[blockIdx.x] = red[0];
}

__global__ void scan_offsets_kernel(int* __restrict__ bsum, int B) {
    if (threadIdx.x == 0 && blockIdx.x == 0) {
        int run = 0;
        for (int i = 0; i < B; ++i) { int v = bsum[i]; bsum[i] = run; run += v; }
    }
}

__global__ void scan_final_kernel(int* __restrict__ data, const int* __restrict__ bsum, int n) {
    __shared__ int tsum[256];
    int t = threadIdx.x;
    int base = blockIdx.x * 2048 + t * 8;
    int v[8];
    int s = 0;
#pragma unroll
    for (int i = 0; i < 8; ++i) {
        v[i] = (base + i < n) ? data[base + i] : 0;
        s += v[i];
    }
    tsum[t] = s;
    for (int off = 1; off < 256; off <<= 1) {
        __syncthreads();
        int u = (t >= off) ? tsum[t - off] : 0;
        __syncthreads();
        tsum[t] += u;
    }
    __syncthreads();
    int run = bsum[blockIdx.x] + tsum[t] - s;
#pragma unroll
    for (int i = 0; i < 8; ++i) {
        run += v[i];
        if (base + i < n) data[base + i] = run;
    }
}

__global__ void partition_kernel(const int* __restrict__ src, const int* __restrict__ dst,
                                 const int* __restrict__ off, unsigned* __restrict__ ebuf,
                                 int E, int NB, int BK) {
    __shared__ int cur[256];
    int t = threadIdx.x;
    if (t < BK) cur[t] = off[t * NB + blockIdx.x];
    __syncthreads();
    int base = blockIdx.x * 8192;
    for (int i = t; i < 8192; i += 256) {
        int e = base + i;
        if (e < E) {
            int d = dst[e];
            int pos = atomicAdd(&cur[d >> 8], 1);
            ebuf[pos] = ((unsigned)src[e] << 8) | (unsigned)(d & 255);
        }
    }
}

__global__ void finalize_kernel(const unsigned* __restrict__ ebuf, const int* __restrict__ off,
                                int* __restrict__ col, int* __restrict__ rowptr,
                                float* __restrict__ dinv, int N, int NB, int E) {
    __shared__ int hist[256], scn[256], cur[256];
    int b = blockIdx.x, t = threadIdx.x;
    int base = off[b * NB];
    int end  = off[(b + 1) * NB];
    int M = end - base;
    hist[t] = 0;
    __syncthreads();
    for (int i = t; i < M; i += 256) atomicAdd(&hist[ebuf[base + i] & 255u], 1);
    __syncthreads();
    scn[t] = hist[t];
    for (int o = 1; o < 256; o <<= 1) {
        __syncthreads();
        int u = (t >= o) ? scn[t - o] : 0;
        __syncthreads();
        scn[t] += u;
    }
    __syncthreads();
    int excl = scn[t] - hist[t];
    int node = b * 256 + t;
    if (node < N) {
        rowptr[node] = base + excl;
        dinv[node] = rsqrtf((float)(hist[t] + 1));
    }
    if (b == 0 && t == 0) rowptr[N] = E;
    cur[t] = base + excl;
    __syncthreads();
    for (int i = t; i < M; i += 256) {
        unsigned w = ebuf[base + i];
        int pos = atomicAdd(&cur[w & 255u], 1);
        col[pos] = (int)(w >> 8);
    }
}

// -------------------------- weight pre-pack --------------------------------
__global__ void packw_kernel(const float* __restrict__ W1l, const float* __restrict__ W1r,
                             const float* __restrict__ W2l, const float* __restrict__ W2r,
                             const float* __restrict__ Wg,
                             unsigned short* __restrict__ p1h, unsigned short* __restrict__ p1l,
                             unsigned short* __restrict__ p2h, unsigned short* __restrict__ p2l,
                             unsigned short* __restrict__ p3h, unsigned short* __restrict__ p3l) {
    int which = blockIdx.y;
    const float* W;
    unsigned short *hi, *lo;
    int K, Mp, colOff, T;
    if (which == 0)      { W = W1l; hi = p1h; lo = p1l; K = 128; Mp = 128; colOff = 0;   T = 16; }
    else if (which == 1) { W = W1r; hi = p1h; lo = p1l; K = 128; Mp = 128; colOff = 128; T = 16; }
    else if (which == 2) { W = W2l; hi = p2h; lo = p2l; K = 128; Mp = 64;  colOff = 0;   T = 8;  }
    else if (which == 3) { W = W2r; hi = p2h; lo = p2l; K = 128; Mp = 64;  colOff = 64;  T = 8;  }
    else                 { W = Wg;  hi = p3h; lo = p3l; K = 64;  Mp = 64;  colOff = 0;   T = 4;  }
    int idx = blockIdx.x * blockDim.x + threadIdx.x;
    if (idx >= K * Mp) return;
    int k = idx / Mp, m = idx % Mp;
    float w = W[(size_t)k * Mp + m];
    int colI = colOff + m;
    int s = k >> 5, kk = k & 31, qq = kk >> 3, j = kk & 7;
    int tt = colI >> 4, n = colI & 15;
    int lane = qq * 16 + n;
    size_t pos = ((size_t)(s * T + tt) * 64 + lane) * 8 + j;
    unsigned short h = f32_bf16_hi(w);
    hi[pos] = h;
    lo[pos] = f32_bf16_hi(w - bf16_to_f32(h));
}

// --------------------------- gemm1 (K=128, M=256) --------------------------
// A-loads hoisted: all 8 float4 issued before any convert/MFMA (one HBM
// latency instead of four). blockIdx.y in {0,1}: tiles 0-7 -> p16, 8-15 -> q16.
__launch_bounds__(256)
__global__ void gemm1_kernel(const float* __restrict__ A,
                             const unsigned short* __restrict__ Whi,
                             const unsigned short* __restrict__ Wlo,
                             __half* __restrict__ outA, __half* __restrict__ outB, int N) {
    constexpr int Ttot = 16, TB = 8;
    const int lane = threadIdx.x & 63;
    const int wave = threadIdx.x >> 6;
    const int m = lane & 15, q = lane >> 4;
    const int t0 = blockIdx.y * TB;
    const int row0 = blockIdx.x * 64 + wave * 16;
    int arow = row0 + m;
    if (arow >= N) arow = N - 1;
    const float* ap = A + (size_t)arow * 128 + q * 8;

    // hoist ALL A loads
    float av[4][8];
#pragma unroll
    for (int s = 0; s < 4; ++s) {
        *(float4*)(av[s])     = *(const float4*)(ap + s * 32);
        *(float4*)(av[s] + 4) = *(const float4*)(ap + s * 32 + 4);
    }
    bf16x8 ahi[4], alo[4];
#pragma unroll
    for (int s = 0; s < 4; ++s)
#pragma unroll
        for (int i = 0; i < 8; ++i) {
            unsigned short h = f32_bf16_hi(av[s][i]);
            ahi[s][i] = (short)h;
            alo[s][i] = (short)f32_bf16_hi(av[s][i] - bf16_to_f32(h));
        }

    f32x4 acc[TB];
#pragma unroll
    for (int t = 0; t < TB; ++t) acc[t] = (f32x4)(0.f);
    const bf16x8* whp = (const bf16x8*)Whi;
    const bf16x8* wlp = (const bf16x8*)Wlo;
#pragma unroll
    for (int s = 0; s < 4; ++s) {
        const int base = (s * Ttot + t0) * 64 + lane;
#pragma unroll
        for (int t = 0; t < TB; ++t) {
            bf16x8 wh = whp[base + t * 64];
            bf16x8 wl = wlp[base + t * 64];
            acc[t] = __builtin_amdgcn_mfma_f32_16x16x32_bf16(ahi[s], wh, acc[t], 0, 0, 0);
            acc[t] = __builtin_amdgcn_mfma_f32_16x16x32_bf16(alo[s], wh, acc[t], 0, 0, 0);
            acc[t] = __builtin_amdgcn_mfma_f32_16x16x32_bf16(ahi[s], wl, acc[t], 0, 0, 0);
        }
    }

#pragma unroll
    for (int r = 0; r < 4; ++r) {
        int row = row0 + q * 4 + r;
        if (row < N) {
            __half* op = (blockIdx.y == 0) ? outA : outB;
#pragma unroll
            for (int t = 0; t < TB; ++t) {
                int c = (t0 + t) * 16 + m - blockIdx.y * 128;
                op[(size_t)row * 128 + c] = __float2half(acc[t][r]);
            }
        }
    }
}

// ------------------- FUSED: agg1+relu+gemm2 (K=128) ------------------------
__launch_bounds__(256)
__global__ void sage2_fused_kernel(const __half* __restrict__ p16, const __half* __restrict__ q16,
                                   const int* __restrict__ rowptr, const int* __restrict__ col,
                                   const float* __restrict__ b1l,
                                   const unsigned short* __restrict__ Whi,
                                   const unsigned short* __restrict__ Wlo,
                                   __half* __restrict__ r16, __half* __restrict__ s16, int N) {
    const int lane = threadIdx.x & 63;
    const int wave = threadIdx.x >> 6;
    const int m = lane & 15, q = lane >> 4;
    const int row0 = blockIdx.x * 64 + wave * 16;
    int node = row0 + m;
    int nclamp = (node < N) ? node : (N - 1);
    int sIdx = rowptr[nclamp];
    int eIdx = (node < N) ? rowptr[nclamp + 1] : sIdx;

    float acc[4][8];
#pragma unroll
    for (int s = 0; s < 4; ++s)
#pragma unroll
        for (int i = 0; i < 8; ++i) acc[s][i] = 0.f;

    const __half* pb = p16 + q * 8;
    int ptr = sIdx;
    for (; ptr + 4 <= eIdx; ptr += 4) {
        int j0 = col[ptr], j1 = col[ptr + 1], j2 = col[ptr + 2], j3 = col[ptr + 3];
        H8 u[4][4];
#pragma unroll
        for (int s = 0; s < 4; ++s) {
            u[0][s].f4 = *(const float4*)(pb + (size_t)j0 * 128 + s * 32);
            u[1][s].f4 = *(const float4*)(pb + (size_t)j1 * 128 + s * 32);
            u[2][s].f4 = *(const float4*)(pb + (size_t)j2 * 128 + s * 32);
            u[3][s].f4 = *(const float4*)(pb + (size_t)j3 * 128 + s * 32);
        }
#pragma unroll
        for (int s = 0; s < 4; ++s)
#pragma unroll
            for (int k = 0; k < 4; ++k) {
                float2 f0 = __half22float2(u[0][s].h[k]);
                float2 f1 = __half22float2(u[1][s].h[k]);
                float2 f2 = __half22float2(u[2][s].h[k]);
                float2 f3 = __half22float2(u[3][s].h[k]);
                acc[s][2 * k]     += (f0.x + f1.x) + (f2.x + f3.x);
                acc[s][2 * k + 1] += (f0.y + f1.y) + (f2.y + f3.y);
            }
    }
    for (; ptr < eIdx; ++ptr) {
        int j0 = col[ptr];
#pragma unroll
        for (int s = 0; s < 4; ++s) {
            H8 u0;
            u0.f4 = *(const float4*)(pb + (size_t)j0 * 128 + s * 32);
#pragma unroll
            for (int k = 0; k < 4; ++k) {
                float2 f0 = __half22float2(u0.h[k]);
                acc[s][2 * k]     += f0.x;
                acc[s][2 * k + 1] += f0.y;
            }
        }
    }

    float inv = 1.0f / fmaxf((float)(eIdx - sIdx), 1.0f);
    bf16x8 ahi[4], alo[4];
#pragma unroll
    for (int s = 0; s < 4; ++s) {
        H8 qv;
        qv.f4 = *(const float4*)(q16 + (size_t)nclamp * 128 + s * 32 + q * 8);
        float bv[8];
        *(float4*)(bv)     = *(const float4*)(b1l + s * 32 + q * 8);
        *(float4*)(bv + 4) = *(const float4*)(b1l + s * 32 + q * 8 + 4);
#pragma unroll
        for (int i = 0; i < 8; ++i) {
            float qf = __half2float(((const __half*)&qv)[i]);
            float h = fmaxf(acc[s][i] * inv + qf + bv[i], 0.f);
            unsigned short hb = f32_bf16_hi(h);
            ahi[s][i] = (short)hb;
            alo[s][i] = (short)f32_bf16_hi(h - bf16_to_f32(hb));
        }
    }

    f32x4 accm[8];
#pragma unroll
    for (int t = 0; t < 8; ++t) accm[t] = (f32x4)(0.f);
    const bf16x8* whp = (const bf16x8*)Whi;
    const bf16x8* wlp = (const bf16x8*)Wlo;
#pragma unroll
    for (int s = 0; s < 4; ++s) {
        const int base = (s * 8) * 64 + lane;
#pragma unroll
        for (int t = 0; t < 8; ++t) {
            bf16x8 wh = whp[base + t * 64];
            bf16x8 wl = wlp[base + t * 64];
            accm[t] = __builtin_amdgcn_mfma_f32_16x16x32_bf16(ahi[s], wh, accm[t], 0, 0, 0);
            accm[t] = __builtin_amdgcn_mfma_f32_16x16x32_bf16(alo[s], wh, accm[t], 0, 0, 0);
            accm[t] = __builtin_amdgcn_mfma_f32_16x16x32_bf16(ahi[s], wl, accm[t], 0, 0, 0);
        }
    }
#pragma unroll
    for (int r = 0; r < 4; ++r) {
        int row = row0 + q * 4 + r;
        if (row < N) {
#pragma unroll
            for (int t = 0; t < 8; ++t) {
                int c = t * 16 + m;
                float v = accm[t][r];
                if (c < 64) r16[(size_t)row * 64 + c] = __float2half(v);
                else        s16[(size_t)row * 64 + (c - 64)] = __float2half(v);
            }
        }
    }
}

// --------------- FUSED: agg2+softmax+gemm3 (K=64, dinv scale) --------------
__launch_bounds__(256)
__global__ void gcn_prep_fused_kernel(const __half* __restrict__ r16, const __half* __restrict__ s16,
                                      const int* __restrict__ rowptr, const int* __restrict__ col,
                                      const float* __restrict__ b2l,
                                      const unsigned short* __restrict__ Whi,
                                      const unsigned short* __restrict__ Wlo,
                                      const float* __restrict__ dinv,
                                      __half* __restrict__ tp16, int N) {
    const int lane = threadIdx.x & 63;
    const int wave = threadIdx.x >> 6;
    const int m = lane & 15, q = lane >> 4;
    const int row0 = blockIdx.x * 64 + wave * 16;
    int node = row0 + m;
    int nclamp = (node < N) ? node : (N - 1);
    int sIdx = rowptr[nclamp];
    int eIdx = (node < N) ? rowptr[nclamp + 1] : sIdx;

    float acc[2][8];
#pragma unroll
    for (int s = 0; s < 2; ++s)
#pragma unroll
        for (int i = 0; i < 8; ++i) acc[s][i] = 0.f;

    const __half* rb = r16 + q * 8;
    int ptr = sIdx;
    for (; ptr + 4 <= eIdx; ptr += 4) {
        int j0 = col[ptr], j1 = col[ptr + 1], j2 = col[ptr + 2], j3 = col[ptr + 3];
        H8 u[4][2];
#pragma unroll
        for (int s = 0; s < 2; ++s) {
            u[0][s].f4 = *(const float4*)(rb + (size_t)j0 * 64 + s * 32);
            u[1][s].f4 = *(const float4*)(rb + (size_t)j1 * 64 + s * 32);
            u[2][s].f4 = *(const float4*)(rb + (size_t)j2 * 64 + s * 32);
            u[3][s].f4 = *(const float4*)(rb + (size_t)j3 * 64 + s * 32);
        }
#pragma unroll
        for (int s = 0; s < 2; ++s)
#pragma unroll
            for (int k = 0; k < 4; ++k) {
                float2 f0 = __half22float2(u[0][s].h[k]);
                float2 f1 = __half22float2(u[1][s].h[k]);
                float2 f2 = __half22float2(u[2][s].h[k]);
                float2 f3 = __half22float2(u[3][s].h[k]);
                acc[s][2 * k]     += (f0.x + f1.x) + (f2.x + f3.x);
                acc[s][2 * k + 1] += (f0.y + f1.y) + (f2.y + f3.y);
            }
    }
    for (; ptr < eIdx; ++ptr) {
        int j0 = col[ptr];
#pragma unroll
        for (int s = 0; s < 2; ++s) {
            H8 u0;
            u0.f4 = *(const float4*)(rb + (size_t)j0 * 64 + s * 32);
#pragma unroll
            for (int k = 0; k < 4; ++k) {
                float2 f0 = __half22float2(u0.h[k]);
                acc[s][2 * k]     += f0.x;
                acc[s][2 * k + 1] += f0.y;
            }
        }
    }

    float inv = 1.0f / fmaxf((float)(eIdx - sIdx), 1.0f);
    float v[2][8];
    float mx = -1e30f;
#pragma unroll
    for (int s = 0; s < 2; ++s) {
        H8 sv;
        sv.f4 = *(const float4*)(s16 + (size_t)nclamp * 64 + s * 32 + q * 8);
        float bv[8];
        *(float4*)(bv)     = *(const float4*)(b2l + s * 32 + q * 8);
        *(float4*)(bv + 4) = *(const float4*)(b2l + s * 32 + q * 8 + 4);
#pragma unroll
        for (int i = 0; i < 8; ++i) {
            float sf = __half2float(((const __half*)&sv)[i]);
            v[s][i] = acc[s][i] * inv + sf + bv[i];
            mx = fmaxf(mx, v[s][i]);
        }
    }
    mx = fmaxf(mx, __shfl_xor(mx, 16, 64));
    mx = fmaxf(mx, __shfl_xor(mx, 32, 64));
    float sm = 0.f;
#pragma unroll
    for (int s = 0; s < 2; ++s)
#pragma unroll
        for (int i = 0; i < 8; ++i) {
            v[s][i] = expf(v[s][i] - mx);
            sm += v[s][i];
        }
    sm += __shfl_xor(sm, 16, 64);
    sm += __shfl_xor(sm, 32, 64);
    float is = 1.0f / sm;

    bf16x8 ahi[2], alo[2];
#pragma unroll
    for (int s = 0; s < 2; ++s)
#pragma unroll
        for (int i = 0; i < 8; ++i) {
            float h = v[s][i] * is;
            unsigned short hb = f32_bf16_hi(h);
            ahi[s][i] = (short)hb;
            alo[s][i] = (short)f32_bf16_hi(h - bf16_to_f32(hb));
        }

    f32x4 accm[4];
#pragma unroll
    for (int t = 0; t < 4; ++t) accm[t] = (f32x4)(0.f);
    const bf16x8* whp = (const bf16x8*)Whi;
    const bf16x8* wlp = (const bf16x8*)Wlo;
#pragma unroll
    for (int s = 0; s < 2; ++s) {
        const int base = (s * 4) * 64 + lane;
#pragma unroll
        for (int t = 0; t < 4; ++t) {
            bf16x8 wh = whp[base + t * 64];
            bf16x8 wl = wlp[base + t * 64];
            accm[t] = __builtin_amdgcn_mfma_f32_16x16x32_bf16(ahi[s], wh, accm[t], 0, 0, 0);
            accm[t] = __builtin_amdgcn_mfma_f32_16x16x32_bf16(alo[s], wh, accm[t], 0, 0, 0);
            accm[t] = __builtin_amdgcn_mfma_f32_16x16x32_bf16(ahi[s], wl, accm[t], 0, 0, 0);
        }
    }
#pragma unroll
    for (int r = 0; r < 4; ++r) {
        int row = row0 + q * 4 + r;
        if (row < N) {
            float sc = dinv[row];
#pragma unroll
            for (int t = 0; t < 4; ++t) {
                int c = t * 16 + m;
                tp16[(size_t)row * 64 + c] = __float2half(accm[t][r] * sc);
            }
        }
    }
}

// ------------------------------ gcn gather ---------------------------------
__global__ void gcn_agg_kernel(const __half* __restrict__ tp,
                               const int* __restrict__ rowptr, const int* __restrict__ col,
                               const float* __restrict__ dinv, const float* __restrict__ bg,
                               float* __restrict__ out, int N) {
    int node = blockIdx.x * 4 + (threadIdx.x >> 6);
    if (node >= N) return;
    int lane = threadIdx.x & 63;
    int s = rowptr[node], e = rowptr[node + 1];
    float a[8];
#pragma unroll
    for (int k = 0; k < 8; ++k) a[k] = 0.f;
    int p = s;
    for (; p + 8 <= e; p += 8) {
#pragma unroll
        for (int k = 0; k < 8; ++k)
            a[k] += __half2float(tp[(size_t)col[p + k] * 64 + lane]);
    }
    for (; p < e; ++p) a[0] += __half2float(tp[(size_t)col[p] * 64 + lane]);
    float acc = ((a[0] + a[1]) + (a[2] + a[3])) + ((a[4] + a[5]) + (a[6] + a[7]));
    float di = dinv[node];
    out[(size_t)node * 64 + lane] =
        (acc + __half2float(tp[(size_t)node * 64 + lane])) * di + bg[lane];
}

extern "C" void kernel_launch(void* const* d_in, const int* in_sizes, int n_in,
                              void* d_out, int out_size, void* d_ws, size_t ws_size,
                              hipStream_t stream) {
    const float* x = (const float*)d_in[0];
    const int* ei = (const int*)d_in[1];    // int32 per harness conversion
    const float* W1l = (const float*)d_in[2];
    const float* b1l = (const float*)d_in[3];
    const float* W1r = (const float*)d_in[4];
    const float* W2l = (const float*)d_in[5];
    const float* b2l = (const float*)d_in[6];
    const float* W2r = (const float*)d_in[7];
    const float* Wg  = (const float*)d_in[8];
    const float* bg  = (const float*)d_in[9];

    const int N = in_sizes[0] / 128;
    const int E = in_sizes[1] / 2;
    const int* srcp = ei;
    const int* dstp = ei + E;

    const int NB = (E + 8191) / 8192;
    const int BK = (N + 255) >> 8;
    const int len = BK * NB;

    // workspace layout
    float* ws = (float*)d_ws;
    float* dinv = ws;                          // N
    __half* p16 = (__half*)(dinv + N);         // N*128 half
    __half* q16 = p16 + (size_t)N * 128;       // N*128 half
    __half* r16 = q16 + (size_t)N * 128;       // N*64 half
    __half* s16 = r16 + (size_t)N * 64;        // N*64 half
    __half* tp16 = s16 + (size_t)N * 64;       // N*64 half
    int* rowptr = (int*)(tp16 + (size_t)N * 64); // N+1
    int* off    = rowptr + (N + 1);            // len+2
    int* colbuf = off + len + 2;               // E
    unsigned* ebuf = (unsigned*)(colbuf + E);  // E
    int* bsum   = (int*)(ebuf + E);            // 32
    uintptr_t up = (uintptr_t)(bsum + 32);
    up = (up + 15) & ~(uintptr_t)15;
    unsigned short* p1h = (unsigned short*)up; // 32768 (128x256)
    unsigned short* p1l = p1h + 32768;
    unsigned short* p2h = p1l + 32768;         // 16384 (128x128)
    unsigned short* p2l = p2h + 16384;
    unsigned short* p3h = p2l + 16384;         // 4096 (64x64)
    unsigned short* p3l = p3h + 4096;

    float* out = (float*)d_out;

    // --- CSR build (radix by dst) ---
    count_kernel<<<NB, 256, 0, stream>>>(dstp, off, E, NB, BK);
    const int sn = len + 1;
    const int SBs = (sn + 2047) / 2048;
    scan_reduce_kernel<<<SBs, 256, 0, stream>>>(off, bsum, sn);
    scan_offsets_kernel<<<1, 64, 0, stream>>>(bsum, SBs);
    scan_final_kernel<<<SBs, 256, 0, stream>>>(off, bsum, sn);
    partition_kernel<<<NB, 256, 0, stream>>>(srcp, dstp, off, ebuf, E, NB, BK);
    finalize_kernel<<<BK, 256, 0, stream>>>(ebuf, off, colbuf, rowptr, dinv, N, NB, E);

    packw_kernel<<<dim3(64, 5), 256, 0, stream>>>(W1l, W1r, W2l, W2r, Wg,
                                                  p1h, p1l, p2h, p2l, p3h, p3l);

    const int gb = (N + 63) / 64;
    const int ab = (N + 3) / 4;

    // gemm1: A-loads hoisted; y=0 -> p16, y=1 -> q16
    gemm1_kernel<<<dim3(gb, 2), 256, 0, stream>>>(x, p1h, p1l, p16, q16, N);

    // fused: h1 = relu(mean(p16)+q16+b1l); [r16|s16] = h1 @ [W2l|W2r]
    sage2_fused_kernel<<<gb, 256, 0, stream>>>(p16, q16, rowptr, colbuf, b1l,
                                               p2h, p2l, r16, s16, N);

    // fused: h2 = softmax(mean(r16)+s16+b2l); tp16 = (h2 @ Wg) * dinv
    gcn_prep_fused_kernel<<<gb, 256, 0, stream>>>(r16, s16, rowptr, colbuf, b2l,
                                                  p3h, p3l, dinv, tp16, N);

    gcn_agg_kernel<<<ab, 256, 0, stream>>>(tp16, rowptr, colbuf, dinv, bg, out, N);
}